// Round 12
// baseline (734.061 us; speedup 1.0000x reference)
//
#include <hip/hip_runtime.h>
#include <hip/hip_bf16.h>
#include <math.h>

#define T_TOK 2048
#define DMODEL 1024
#define NH 16
#define HD 64
#define S_LEN 1024
#define NE 8
#define CAP 256
#define DFF 4096

typedef __attribute__((ext_vector_type(8))) short bf16x8;
typedef __attribute__((ext_vector_type(4))) float f32x4;

__device__ inline unsigned short f2bf(float f) {
    union { float f; unsigned int u; } x; x.f = f;
    unsigned int u = x.u;
    unsigned int r = (u + 0x7FFFu + ((u >> 16) & 1u)) >> 16;
    return (unsigned short)r;
}

__device__ inline float bf2f(unsigned short h) {
    union { unsigned int u; float f; } x; x.u = (unsigned int)h << 16; return x.f;
}

// packed f32x2 -> bf16x2 (RTNE); lo in low 16 bits
__device__ inline unsigned int pkbf(float lo, float hi) {
    __hip_bfloat162 h2 = __float22bfloat162_rn(make_float2(lo, hi));
    unsigned int r;
    __builtin_memcpy(&r, &h2, 4);
    return r;
}

__device__ inline void gload16(const void* g, void* l) {
    __builtin_amdgcn_global_load_lds(
        (const __attribute__((address_space(1))) unsigned int*)g,
        (__attribute__((address_space(3))) unsigned int*)l, 16, 0, 0);
}

// ---------------- RoPE table (+ gsum zero) ----------------
__global__ void rope_table_kernel(float* __restrict__ rc, float* __restrict__ rs,
                                  float* __restrict__ gsum) {
    int s = blockIdx.x;
    int i = threadIdx.x;
    float invf = powf(10000.0f, -(float)(2 * i) / 64.0f);
    float ang = (float)s * invf;
    rc[s * 32 + i] = cosf(ang);
    rs[s * 32 + i] = sinf(ang);
    if (blockIdx.x == 0 && threadIdx.x < 8) gsum[threadIdx.x] = 0.f;
}

// ---------------- global-token scan: packed indices + count per batch ----------------
__global__ __launch_bounds__(1024) void gscan_kernel(const int* __restrict__ gtm,
                                                     int* __restrict__ gidx,
                                                     int* __restrict__ gcnt) {
    __shared__ int ps[1024];
    int b = blockIdx.x, t = threadIdx.x;
    int f = gtm[b * 1024 + t] ? 1 : 0;
    ps[t] = f;
    __syncthreads();
    for (int off = 1; off < 1024; off <<= 1) {
        int v = (t >= off) ? ps[t - off] : 0;
        __syncthreads();
        ps[t] += v;
        __syncthreads();
    }
    if (f) {
        int pos = ps[t] - 1;
        if (pos < 128) gidx[b * 128 + pos] = t;
    }
    if (t == 1023) gcnt[b] = ps[1023] > 128 ? 128 : ps[1023];
}

// ---------------- RMSNorm (bf16 out) ----------------
__global__ __launch_bounds__(256) void rmsnorm_kernel(const float* __restrict__ x,
                                                      const float* __restrict__ g,
                                                      unsigned short* __restrict__ y) {
    __shared__ float red[256];
    int t = blockIdx.x;
    int tid = threadIdx.x;
    const float* xr = x + (size_t)t * DMODEL;
    float ss = 0.f;
    for (int d = tid; d < DMODEL; d += 256) { float v = xr[d]; ss += v * v; }
    red[tid] = ss; __syncthreads();
    for (int o = 128; o > 0; o >>= 1) { if (tid < o) red[tid] += red[tid + o]; __syncthreads(); }
    float scale = 1.0f / sqrtf(red[0] / (float)DMODEL + 1e-6f);
    unsigned short* yr = y + (size_t)t * DMODEL;
    for (int d = tid; d < DMODEL; d += 256) yr[d] = f2bf(g[d] * xr[d] * scale);
}

// ---------------- fused RMSNorm + gate (per token) ----------------
__global__ __launch_bounds__(256) void rmsnorm_gate_kernel(const float* __restrict__ x,
                                                           const float* __restrict__ g,
                                                           const float* __restrict__ Wgate,
                                                           float* __restrict__ y,
                                                           float* __restrict__ wfull,
                                                           int* __restrict__ slot,
                                                           float* __restrict__ gate_sum) {
    __shared__ float red[256];
    __shared__ float lg[8];
    int t = blockIdx.x, tid = threadIdx.x;
    const float* xr = x + (size_t)t * DMODEL;
    float xv[4]; float ss = 0.f;
    #pragma unroll
    for (int i = 0; i < 4; i++) { xv[i] = xr[tid + i * 256]; ss += xv[i] * xv[i]; }
    red[tid] = ss; __syncthreads();
    for (int o = 128; o > 0; o >>= 1) { if (tid < o) red[tid] += red[tid + o]; __syncthreads(); }
    float scale = 1.0f / sqrtf(red[0] / (float)DMODEL + 1e-6f);
    float part[8] = {};
    float* yr = y + (size_t)t * DMODEL;
    #pragma unroll
    for (int i = 0; i < 4; i++) {
        int d = tid + i * 256;
        float yv = g[d] * xv[i] * scale;
        yr[d] = yv;
        const float* wg = Wgate + d * 8;
        #pragma unroll
        for (int e = 0; e < 8; e++) part[e] += yv * wg[e];
    }
    __syncthreads();
    for (int e = 0; e < 8; e++) {
        red[tid] = part[e]; __syncthreads();
        for (int o = 128; o > 0; o >>= 1) { if (tid < o) red[tid] += red[tid + o]; __syncthreads(); }
        if (tid == 0) lg[e] = red[0];
        __syncthreads();
    }
    if (tid == 0) {
        float mx = lg[0];
        #pragma unroll
        for (int e = 1; e < 8; e++) mx = fmaxf(mx, lg[e]);
        float pr[8]; float s = 0.f;
        #pragma unroll
        for (int e = 0; e < 8; e++) { pr[e] = __expf(lg[e] - mx); s += pr[e]; }
        float inv = 1.0f / s;
        int e1 = 0; float v1 = -1.f;
        #pragma unroll
        for (int e = 0; e < 8; e++) {
            pr[e] *= inv;
            atomicAdd(&gate_sum[e], pr[e]);
            if (pr[e] > v1) { v1 = pr[e]; e1 = e; }
        }
        int e2 = -1; float v2 = -1.f;
        #pragma unroll
        for (int e = 0; e < 8; e++) {
            if (e == e1) continue;
            if (pr[e] > v2) { v2 = pr[e]; e2 = e; }
        }
        #pragma unroll
        for (int e = 0; e < 8; e++) {
            wfull[t * 8 + e] = (e == e1) ? v1 : (e == e2) ? v2 : 0.f;
            slot[t * 8 + e] = -1;
        }
    }
}

// ---------------- fused QKV GEMM + RoPE + hi/lo + V-transpose (B reg-prefetch) ----------------
__global__ __launch_bounds__(256) void gemm_qkv_rope(const unsigned short* __restrict__ xn,
                                                     const float* __restrict__ Wq,
                                                     const float* __restrict__ Wk,
                                                     const float* __restrict__ Wv,
                                                     const float* __restrict__ rc,
                                                     const float* __restrict__ rs,
                                                     unsigned short* __restrict__ Qh,
                                                     unsigned short* __restrict__ Ql,
                                                     unsigned short* __restrict__ Kh,
                                                     unsigned short* __restrict__ Kl,
                                                     unsigned short* __restrict__ Vtb) {
    __shared__ unsigned short As[128 * 64];
    __shared__ unsigned int Bp[64 * 32];
    const int mat = blockIdx.x >> 4;
    const int h = blockIdx.x & 15;
    const float* B = ((mat == 0) ? Wq : (mat == 1) ? Wk : Wv) + h * 64;
    const int by = blockIdx.y * 128;
    const int tid = threadIdx.x, l = tid & 63, wid = tid >> 6;
    const int g = l >> 4;
    const int kp = tid >> 3;
    const int nc = tid & 7;
    const int chunk = kp >> 2, within = kp & 3;

    f32x4 acc[2][4] = {};

    const float* Brow = B + (size_t)(2 * kp) * 1024 + nc * 8;
    float4 a0 = *(const float4*)(Brow);
    float4 a1 = *(const float4*)(Brow + 4);
    float4 b0 = *(const float4*)(Brow + 1024);
    float4 b1 = *(const float4*)(Brow + 1028);

    for (int k0 = 0; k0 < 1024; k0 += 64) {
        #pragma unroll
        for (int i = 0; i < 4; i++) {
            int c = i * 256 + tid;
            int row = c >> 3, sl = c & 7, gs = sl ^ (row & 7);
            gload16(xn + (size_t)(by + row) * 1024 + k0 + gs * 8, &As[c * 8]);
        }
        unsigned int p[8];
        p[0] = pkbf(a0.x, b0.x); p[1] = pkbf(a0.y, b0.y);
        p[2] = pkbf(a0.z, b0.z); p[3] = pkbf(a0.w, b0.w);
        p[4] = pkbf(a1.x, b1.x); p[5] = pkbf(a1.y, b1.y);
        p[6] = pkbf(a1.z, b1.z); p[7] = pkbf(a1.w, b1.w);
        #pragma unroll
        for (int i = 0; i < 8; i++) {
            int n_loc = nc * 8 + i;
            int idx = n_loc * 32 + ((chunk ^ (n_loc & 7)) << 2) + within;
            Bp[idx] = p[i];
        }
        __syncthreads();
        if (k0 + 64 < 1024) {
            const float* Bn = B + (size_t)(k0 + 64 + 2 * kp) * 1024 + nc * 8;
            a0 = *(const float4*)(Bn);
            a1 = *(const float4*)(Bn + 4);
            b0 = *(const float4*)(Bn + 1024);
            b1 = *(const float4*)(Bn + 1028);
        }
        #pragma unroll
        for (int ks = 0; ks < 2; ks++) {
            bf16x8 af[2];
            #pragma unroll
            for (int m = 0; m < 2; m++) {
                int row = wid * 32 + m * 16 + (l & 15);
                int sl = (ks * 4 + g) ^ (row & 7);
                af[m] = *(const bf16x8*)&As[row * 64 + sl * 8];
            }
            #pragma unroll
            for (int nf = 0; nf < 4; nf++) {
                int n_loc = nf * 16 + (l & 15);
                int base = n_loc * 32 + (((ks * 4 + g) ^ (n_loc & 7)) << 2);
                bf16x8 bfr = *(const bf16x8*)&Bp[base];
                #pragma unroll
                for (int m = 0; m < 2; m++)
                    acc[m][nf] = __builtin_amdgcn_mfma_f32_16x16x32_bf16(af[m], bfr, acc[m][nf], 0, 0, 0);
            }
        }
        __syncthreads();
    }

    if (mat < 2) {
        unsigned short* Dh = (mat == 0) ? Qh : Kh;
        unsigned short* Dl = (mat == 0) ? Ql : Kl;
        float scale = (mat == 0) ? 0.125f : 1.0f;
        #pragma unroll
        for (int m = 0; m < 2; m++)
            #pragma unroll
            for (int r = 0; r < 4; r++) {
                int t = by + wid * 32 + m * 16 + g * 4 + r;
                int b = t >> 10, s = t & 1023;
                size_t ob = ((size_t)(b * 16 + h) * 1024 + s) * 64;
                #pragma unroll
                for (int pr = 0; pr < 2; pr++) {
                    int i = pr * 16 + (l & 15);
                    float c = rc[s * 32 + i], sn = rs[s * 32 + i];
                    float a = acc[m][pr][r], bb = acc[m][pr + 2][r];
                    float v0 = (a * c - bb * sn) * scale;
                    float v1 = (bb * c + a * sn) * scale;
                    unsigned short h0 = f2bf(v0), h1 = f2bf(v1);
                    Dh[ob + i] = h0;      Dl[ob + i] = f2bf(v0 - bf2f(h0));
                    Dh[ob + i + 32] = h1; Dl[ob + i + 32] = f2bf(v1 - bf2f(h1));
                }
            }
    } else {
        #pragma unroll
        for (int m = 0; m < 2; m++) {
            int t0 = by + wid * 32 + m * 16 + g * 4;
            int b = t0 >> 10, s0 = t0 & 1023;
            #pragma unroll
            for (int nf = 0; nf < 4; nf++) {
                int d = nf * 16 + (l & 15);
                unsigned short tmp[4];
                #pragma unroll
                for (int r = 0; r < 4; r++) tmp[r] = f2bf(acc[m][nf][r]);
                *(uint2*)&Vtb[((size_t)(b * 16 + h) * 64 + d) * 1024 + s0] = *(uint2*)tmp;
            }
        }
    }
}

// ---------------- gather global-token K/V into packed tiles ----------------
__global__ __launch_bounds__(256) void gather_gkv_kernel(const unsigned short* __restrict__ Kh,
                                                         const unsigned short* __restrict__ Kl,
                                                         const unsigned short* __restrict__ Vtb,
                                                         const int* __restrict__ gidx,
                                                         const int* __restrict__ gcnt,
                                                         unsigned short* __restrict__ Kgh,
                                                         unsigned short* __restrict__ Kgl,
                                                         unsigned short* __restrict__ Vgt) {
    int bh = blockIdx.x;
    int b = bh >> 4;
    int cnt = gcnt[b];
    int tid = threadIdx.x;
    for (int i = tid; i < 128 * 8; i += 256) {
        int slot = i >> 3, c8 = (i & 7) * 8;
        size_t dst = ((size_t)bh * 128 + slot) * 64 + c8;
        if (slot < cnt) {
            int idx = gidx[b * 128 + slot];
            size_t src = ((size_t)bh * 1024 + idx) * 64 + c8;
            *(uint4*)(Kgh + dst) = *(const uint4*)(Kh + src);
            *(uint4*)(Kgl + dst) = *(const uint4*)(Kl + src);
        } else {
            uint4 z = {0, 0, 0, 0};
            *(uint4*)(Kgh + dst) = z;
            *(uint4*)(Kgl + dst) = z;
        }
    }
    for (int i = tid; i < 64 * 16; i += 256) {
        int d = i >> 4, s8 = (i & 15) * 8;
        unsigned short tmp[8];
        #pragma unroll
        for (int u = 0; u < 8; u++) {
            int slot = s8 + u;
            tmp[u] = (slot < cnt) ? Vtb[((size_t)bh * 64 + d) * 1024 + gidx[b * 128 + slot]]
                                  : (unsigned short)0;
        }
        *(uint4*)(Vgt + ((size_t)bh * 64 + d) * 128 + s8) = *(uint4*)tmp;
    }
}

// ---------------- sparse flash attention: window tiles + gathered global tiles ----------------
__global__ __launch_bounds__(256) void attn_mfma_kernel(const unsigned short* __restrict__ Qh,
                                                        const unsigned short* __restrict__ Ql,
                                                        const unsigned short* __restrict__ Kh,
                                                        const unsigned short* __restrict__ Kl,
                                                        const unsigned short* __restrict__ Vtb,
                                                        const unsigned short* __restrict__ Kgh,
                                                        const unsigned short* __restrict__ Kgl,
                                                        const unsigned short* __restrict__ Vgt,
                                                        const int* __restrict__ gtm,
                                                        const int* __restrict__ gcnt,
                                                        unsigned short* __restrict__ o) {
    __shared__ unsigned short Ksh[2][64 * 64];
    __shared__ unsigned short Ksl[2][64 * 64];
    __shared__ unsigned short Vs[2][64 * 64];
    __shared__ unsigned short Pl[4][16 * 64];
    const int qt = blockIdx.x, h = blockIdx.y, b = blockIdx.z;
    const int bh = b * 16 + h;
    const int tid = threadIdx.x, l = tid & 63, w = tid >> 6;
    const int q0 = qt * 64 + w * 16;
    const int jt_lo = (qt >= 4) ? (qt - 4) : 0;
    const int nwin = qt - jt_lo + 1;
    const int ntiles = nwin + 2;
    const int cnt = gcnt[b];
    const unsigned short* Qhb = Qh + (size_t)bh * 1024 * 64;
    const unsigned short* Qlb = Ql + (size_t)bh * 1024 * 64;
    const unsigned short* Khb = Kh + (size_t)bh * 1024 * 64;
    const unsigned short* Klb = Kl + (size_t)bh * 1024 * 64;
    const unsigned short* Vbh = Vtb + (size_t)bh * 64 * 1024;
    const unsigned short* Kghb = Kgh + (size_t)bh * 128 * 64;
    const unsigned short* Kglb = Kgl + (size_t)bh * 128 * 64;
    const unsigned short* Vgtb = Vgt + (size_t)bh * 64 * 128;
    const int* gb = gtm + b * 1024;

    bf16x8 afh[2], afl[2];
    #pragma unroll
    for (int ks = 0; ks < 2; ks++) {
        size_t off = (size_t)(q0 + (l & 15)) * 64 + ks * 32 + (l >> 4) * 8;
        afh[ks] = *(const bf16x8*)(Qhb + off);
        afl[ks] = *(const bf16x8*)(Qlb + off);
    }

    f32x4 acc_o[4] = {};
    float m_run[4], l_run[4];
    #pragma unroll
    for (int r = 0; r < 4; r++) { m_run[r] = -1e30f; l_run[r] = 0.f; }

    auto STAGE = [&](int ti, int buf) {
        if (ti < nwin) {
            int j0s = (jt_lo + ti) * 64;
            #pragma unroll
            for (int i = 0; i < 2; i++) {
                int c = i * 256 + tid, row = c >> 3, sl = c & 7, gs = sl ^ (row & 7);
                gload16(Khb + (size_t)(j0s + row) * 64 + gs * 8, &Ksh[buf][c * 8]);
                gload16(Klb + (size_t)(j0s + row) * 64 + gs * 8, &Ksl[buf][c * 8]);
                gload16(Vbh + (size_t)row * 1024 + j0s + gs * 8, &Vs[buf][c * 8]);
            }
        } else {
            int g0 = (ti - nwin) * 64;
            #pragma unroll
            for (int i = 0; i < 2; i++) {
                int c = i * 256 + tid, row = c >> 3, sl = c & 7, gs = sl ^ (row & 7);
                gload16(Kghb + (size_t)(g0 + row) * 64 + gs * 8, &Ksh[buf][c * 8]);
                gload16(Kglb + (size_t)(g0 + row) * 64 + gs * 8, &Ksl[buf][c * 8]);
                gload16(Vgtb + (size_t)row * 128 + g0 + gs * 8, &Vs[buf][c * 8]);
            }
        }
    };

    STAGE(0, 0);
    int cur = 0;

    for (int ti = 0; ti < ntiles; ti++) {
        __syncthreads();
        if (ti + 1 < ntiles) STAGE(ti + 1, cur ^ 1);

        f32x4 sv[4] = {};
        __builtin_amdgcn_s_setprio(1);
        #pragma unroll
        for (int n = 0; n < 4; n++) {
            #pragma unroll
            for (int ks = 0; ks < 2; ks++) {
                int row = n * 16 + (l & 15);
                int sl = (ks * 4 + (l >> 4)) ^ (row & 7);
                bf16x8 khf = *(const bf16x8*)&Ksh[cur][row * 64 + sl * 8];
                bf16x8 klf = *(const bf16x8*)&Ksl[cur][row * 64 + sl * 8];
                sv[n] = __builtin_amdgcn_mfma_f32_16x16x32_bf16(afl[ks], khf, sv[n], 0, 0, 0);
                sv[n] = __builtin_amdgcn_mfma_f32_16x16x32_bf16(afh[ks], klf, sv[n], 0, 0, 0);
                sv[n] = __builtin_amdgcn_mfma_f32_16x16x32_bf16(afh[ks], khf, sv[n], 0, 0, 0);
            }
        }
        __builtin_amdgcn_s_setprio(0);

        if (ti < nwin) {
            int j0 = (jt_lo + ti) * 64;
            int gk[4];
            #pragma unroll
            for (int n = 0; n < 4; n++) gk[n] = gb[j0 + n * 16 + (l & 15)];
            #pragma unroll
            for (int n = 0; n < 4; n++)
                #pragma unroll
                for (int r = 0; r < 4; r++) {
                    int q = q0 + (l >> 4) * 4 + r;
                    int k = j0 + n * 16 + (l & 15);
                    bool allowed = (k <= q) && (q - k < 256) && !gk[n];
                    if (!allowed) sv[n][r] = -1e30f;
                }
        } else {
            int s0 = (ti - nwin) * 64;
            #pragma unroll
            for (int n = 0; n < 4; n++) {
                int slot = s0 + n * 16 + (l & 15);
                bool allowed = slot < cnt;
                #pragma unroll
                for (int r = 0; r < 4; r++)
                    if (!allowed) sv[n][r] = -1e30f;
            }
        }

        {
            float tm[4], corr[4], rsum[4];
            #pragma unroll
            for (int r = 0; r < 4; r++)
                tm[r] = fmaxf(fmaxf(sv[0][r], sv[1][r]), fmaxf(sv[2][r], sv[3][r]));
            #pragma unroll
            for (int wd = 1; wd <= 8; wd <<= 1)
                #pragma unroll
                for (int r = 0; r < 4; r++) tm[r] = fmaxf(tm[r], __shfl_xor(tm[r], wd, 64));
            #pragma unroll
            for (int r = 0; r < 4; r++) {
                float mn = fmaxf(m_run[r], tm[r]);
                corr[r] = __expf(m_run[r] - mn);
                m_run[r] = mn;
                rsum[r] = 0.f;
            }
            #pragma unroll
            for (int n = 0; n < 4; n++)
                #pragma unroll
                for (int r = 0; r < 4; r++) {
                    float p = __expf(sv[n][r] - m_run[r]);
                    sv[n][r] = p;
                    rsum[r] += p;
                }
            #pragma unroll
            for (int wd = 1; wd <= 8; wd <<= 1)
                #pragma unroll
                for (int r = 0; r < 4; r++) rsum[r] += __shfl_xor(rsum[r], wd, 64);
            #pragma unroll
            for (int r = 0; r < 4; r++) l_run[r] = l_run[r] * corr[r] + rsum[r];
            #pragma unroll
            for (int nd = 0; nd < 4; nd++)
                #pragma unroll
                for (int r = 0; r < 4; r++) acc_o[nd][r] *= corr[r];
            #pragma unroll
            for (int n = 0; n < 4; n++)
                #pragma unroll
                for (int r = 0; r < 4; r++) {
                    int qr = (l >> 4) * 4 + r;
                    int kc = n * 16 + (l & 15);
                    int byte = (qr * 128 + kc * 2) ^ ((qr & 7) << 4);
                    Pl[w][byte >> 1] = f2bf(sv[n][r]);
                }
        }

        asm volatile("s_waitcnt lgkmcnt(0)" ::: "memory");
        __builtin_amdgcn_sched_barrier(0);

        __builtin_amdgcn_s_setprio(1);
        #pragma unroll
        for (int ks = 0; ks < 2; ks++) {
            int prow = l & 15;
            int psl = (ks * 4 + (l >> 4)) ^ (prow & 7);
            bf16x8 pa = *(const bf16x8*)&Pl[w][prow * 64 + psl * 8];
            #pragma unroll
            for (int nd = 0; nd < 4; nd++) {
                int row = nd * 16 + (l & 15);
                int sl = (ks * 4 + (l >> 4)) ^ (row & 7);
                bf16x8 vf = *(const bf16x8*)&Vs[cur][row * 64 + sl * 8];
                acc_o[nd] = __builtin_amdgcn_mfma_f32_16x16x32_bf16(pa, vf, acc_o[nd], 0, 0, 0);
            }
        }
        __builtin_amdgcn_s_setprio(0);
        cur ^= 1;
    }

    #pragma unroll
    for (int r = 0; r < 4; r++) {
        float inv = 1.0f / l_run[r];
        int t_ = b * 1024 + q0 + (l >> 4) * 4 + r;
        #pragma unroll
        for (int nd = 0; nd < 4; nd++) {
            int col = h * 64 + nd * 16 + (l & 15);
            o[(size_t)t_ * 1024 + col] = f2bf(acc_o[nd][r] * inv);
        }
    }
}

// ---------------- exact full-row attention for global-q tokens (overwrites attno rows) ----------------
__global__ __launch_bounds__(256) void attn_fixup_kernel(const unsigned short* __restrict__ Qh,
                                                         const unsigned short* __restrict__ Ql,
                                                         const unsigned short* __restrict__ Kh,
                                                         const unsigned short* __restrict__ Kl,
                                                         const unsigned short* __restrict__ Vtb,
                                                         const int* __restrict__ gidx,
                                                         const int* __restrict__ gcnt,
                                                         unsigned short* __restrict__ o) {
    int slot = blockIdx.x, h = blockIdx.y, b = blockIdx.z;
    if (slot >= gcnt[b]) return;
    int t = gidx[b * 128 + slot];
    int bh = b * 16 + h;
    __shared__ float qf[64];
    __shared__ float sc[1024];
    __shared__ float red[256];
    __shared__ float pacc[4][64];
    int tid = threadIdx.x;
    if (tid < 64) {
        size_t qo = ((size_t)bh * 1024 + t) * 64 + tid;
        qf[tid] = bf2f(Qh[qo]) + bf2f(Ql[qo]);
    }
    __syncthreads();
    float myS[4];
    #pragma unroll
    for (int jj = 0; jj < 4; jj++) {
        int k = jj * 256 + tid;
        const uint4* kh4 = (const uint4*)(Kh + ((size_t)bh * 1024 + k) * 64);
        const uint4* kl4 = (const uint4*)(Kl + ((size_t)bh * 1024 + k) * 64);
        float acc = 0.f;
        #pragma unroll
        for (int c = 0; c < 8; c++) {
            union { uint4 v; unsigned short s[8]; } uh, ul;
            uh.v = kh4[c]; ul.v = kl4[c];
            #pragma unroll
            for (int u = 0; u < 8; u++)
                acc += qf[c * 8 + u] * (bf2f(uh.s[u]) + bf2f(ul.s[u]));
        }
        myS[jj] = acc;
    }
    float m = fmaxf(fmaxf(myS[0], myS[1]), fmaxf(myS[2], myS[3]));
    red[tid] = m; __syncthreads();
    for (int off = 128; off > 0; off >>= 1) { if (tid < off) red[tid] = fmaxf(red[tid], red[tid + off]); __syncthreads(); }
    m = red[0]; __syncthreads();
    float s = 0.f;
    #pragma unroll
    for (int jj = 0; jj < 4; jj++) {
        float p = __expf(myS[jj] - m);
        sc[jj * 256 + tid] = p;
        s += p;
    }
    red[tid] = s; __syncthreads();
    for (int off = 128; off > 0; off >>= 1) { if (tid < off) red[tid] += red[tid + off]; __syncthreads(); }
    float inv = 1.0f / red[0];
    __syncthreads();
    int dd = tid & 63, jg = tid >> 6;
    const unsigned short* vrow = Vtb + ((size_t)bh * 64 + dd) * 1024;
    float acc = 0.f;
    for (int i = 0; i < 256; i++) {
        int j = jg * 256 + i;
        acc += sc[j] * bf2f(vrow[j]);
    }
    pacc[jg][dd] = acc; __syncthreads();
    if (tid < 64) {
        float sum = pacc[0][tid] + pacc[1][tid] + pacc[2][tid] + pacc[3][tid];
        o[((size_t)(b * 1024 + t)) * 1024 + h * 64 + tid] = f2bf(sum * inv);
    }
}

// ---------------- generic fused GEMM: C(f32) = A(bf16) @ B(f32), B reg-prefetch ----------------
template <int RES>
__global__ __launch_bounds__(256) void gemm_bf32(const unsigned short* __restrict__ A,
                                                 const float* __restrict__ B,
                                                 const float* __restrict__ Rr,
                                                 float* __restrict__ C,
                                                 int K, int lda,
                                                 long long sA, long long sB, long long sC) {
    __shared__ unsigned short As[128 * 64];
    __shared__ unsigned int Bp[32 * 32];
    A += (long long)blockIdx.z * sA + (long long)blockIdx.y * 128 * lda;
    B += (long long)blockIdx.z * sB;
    C += (long long)blockIdx.z * sC + (long long)blockIdx.y * 128 * 1024;
    const float* Rp = RES ? (Rr + (long long)blockIdx.y * 128 * 1024) : nullptr;
    const int bx = blockIdx.x * 32;
    const int tid = threadIdx.x, l = tid & 63, wid = tid >> 6;
    const int g = l >> 4;
    const int kp = tid >> 3;
    const int nc = tid & 7;
    const int chunk = kp >> 2, within = kp & 3;

    f32x4 acc[2][2] = {};

    const float* Brow = B + (size_t)(2 * kp) * 1024 + bx + nc * 4;
    float4 a0 = *(const float4*)(Brow);
    float4 a1 = *(const float4*)(Brow + 1024);

    for (int k0 = 0; k0 < K; k0 += 64) {
        #pragma unroll
        for (int i = 0; i < 4; i++) {
            int c = i * 256 + tid;
            int row = c >> 3, sl = c & 7, gs = sl ^ (row & 7);
            gload16(A + (size_t)row * lda + k0 + gs * 8, &As[c * 8]);
        }
        unsigned int p1[4];
        p1[0] = pkbf(a0.x, a1.x); p1[1] = pkbf(a0.y, a1.y);
        p1[2] = pkbf(a0.z, a1.z); p1[3] = pkbf(a0.w, a1.w);
        #pragma unroll
        for (int i = 0; i < 4; i++) {
            int n_loc = nc * 4 + i;
            int idx = n_loc * 32 + ((chunk ^ (n_loc & 7)) << 2) + within;
            Bp[idx] = p1[i];
        }
        __syncthreads();
        if (k0 + 64 < K) {
            const float* Bn = B + (size_t)(k0 + 64 + 2 * kp) * 1024 + bx + nc * 4;
            a0 = *(const float4*)(Bn);
            a1 = *(const float4*)(Bn + 1024);
        }
        #pragma unroll
        for (int ks = 0; ks < 2; ks++) {
            bf16x8 af[2];
            #pragma unroll
            for (int m = 0; m < 2; m++) {
                int row = wid * 32 + m * 16 + (l & 15);
                int sl = (ks * 4 + g) ^ (row & 7);
                af[m] = *(const bf16x8*)&As[row * 64 + sl * 8];
            }
            #pragma unroll
            for (int nf = 0; nf < 2; nf++) {
                int n_loc = nf * 16 + (l & 15);
                int base = n_loc * 32 + (((ks * 4 + g) ^ (n_loc & 7)) << 2);
                bf16x8 bfr = *(const bf16x8*)&Bp[base];
                #pragma unroll
                for (int m = 0; m < 2; m++)
                    acc[m][nf] = __builtin_amdgcn_mfma_f32_16x16x32_bf16(af[m], bfr, acc[m][nf], 0, 0, 0);
            }
        }
        __syncthreads();
    }
    #pragma unroll
    for (int m = 0; m < 2; m++) {
        int row0 = wid * 32 + m * 16 + g * 4;
        #pragma unroll
        for (int nf = 0; nf < 2; nf++) {
            int col = bx + nf * 16 + (l & 15);
            #pragma unroll
            for (int r = 0; r < 4; r++) {
                size_t idx = (size_t)(row0 + r) * 1024 + col;
                float v = acc[m][nf][r];
                if (RES) v += Rp[idx];
                C[idx] = v;
            }
        }
    }
}

// ---------------- fused MoE W1 GEMM + SwiGLU (B reg-prefetch) ----------------
__global__ __launch_bounds__(256) void gemm_w1_fused(const unsigned short* __restrict__ tok,
                                                     const float* __restrict__ W1,
                                                     unsigned short* __restrict__ act) {
    __shared__ unsigned short As[256 * 64];
    __shared__ unsigned int B1p[32 * 32];
    __shared__ unsigned int B2p[32 * 32];
    const int e = blockIdx.y;
    const int bx = blockIdx.x * 32;
    const unsigned short* A = tok + (size_t)e * CAP * DMODEL;
    const float* B = W1 + (size_t)e * DMODEL * (2 * DFF);
    unsigned short* C = act + (size_t)e * CAP * DFF;
    const int tid = threadIdx.x, l = tid & 63, wid = tid >> 6;
    const int g = l >> 4;
    const int kp = tid >> 3;
    const int nc = tid & 7;
    const int chunk = kp >> 2, within = kp & 3;

    f32x4 acc1[4][2] = {};
    f32x4 acc2[4][2] = {};

    const float* Brow = B + (size_t)(2 * kp) * 8192 + bx + nc * 4;
    float4 a0 = *(const float4*)(Brow);
    float4 a1 = *(const float4*)(Brow + 8192);
    float4 c0 = *(const float4*)(Brow + 4096);
    float4 c1 = *(const float4*)(Brow + 4096 + 8192);

    for (int k0 = 0; k0 < DMODEL; k0 += 64) {
        #pragma unroll
        for (int i = 0; i < 8; i++) {
            int c = i * 256 + tid;
            int row = c >> 3, sl = c & 7, gs = sl ^ (row & 7);
            gload16(A + (size_t)row * DMODEL + k0 + gs * 8, &As[c * 8]);
        }
        unsigned int p1[4], p2[4];
        p1[0] = pkbf(a0.x, a1.x); p1[1] = pkbf(a0.y, a1.y);
        p1[2] = pkbf(a0.z, a1.z); p1[3] = pkbf(a0.w, a1.w);
        p2[0] = pkbf(c0.x, c1.x); p2[1] = pkbf(c0.y, c1.y);
        p2[2] = pkbf(c0.z, c1.z); p2[3] = pkbf(c0.w, c1.w);
        #pragma unroll
        for (int i = 0; i < 4; i++) {
            int n_loc = nc * 4 + i;
            int idx = n_loc * 32 + ((chunk ^ (n_loc & 7)) << 2) + within;
            B1p[idx] = p1[i];
            B2p[idx] = p2[i];
        }
        __syncthreads();
        if (k0 + 64 < DMODEL) {
            const float* Bn = B + (size_t)(k0 + 64 + 2 * kp) * 8192 + bx + nc * 4;
            a0 = *(const float4*)(Bn);
            a1 = *(const float4*)(Bn + 8192);
            c0 = *(const float4*)(Bn + 4096);
            c1 = *(const float4*)(Bn + 4096 + 8192);
        }
        #pragma unroll
        for (int ks = 0; ks < 2; ks++) {
            bf16x8 af[4];
            #pragma unroll
            for (int m = 0; m < 4; m++) {
                int row = wid * 64 + m * 16 + (l & 15);
                int sl = (ks * 4 + g) ^ (row & 7);
                af[m] = *(const bf16x8*)&As[row * 64 + sl * 8];
            }
            #pragma unroll
            for (int nf = 0; nf < 2; nf++) {
                int n_loc = nf * 16 + (l & 15);
                int base = n_loc * 32 + (((ks * 4 + g) ^ (n_loc & 7)) << 2);
                bf16x8 b1 = *(const bf16x8*)&B1p[base];
                bf16x8 b2 = *(const bf16x8*)&B2p[base];
                #pragma unroll
                for (int m = 0; m < 4; m++) {
                    acc1[m][nf] = __builtin_amdgcn_mfma_f32_16x16x32_bf16(af[m], b1, acc1[m][nf], 0, 0, 0);
                    acc2[m][nf] = __builtin_amdgcn_mfma_f32_16x16x32_bf16(af[m], b2, acc2[m][nf], 0, 0, 0);
                }
            }
        }
        __syncthreads();
    }
    #pragma unroll
    for (int m = 0; m < 4; m++) {
        int row0 = wid * 64 + m * 16 + g * 4;
        #pragma unroll
        for (int nf = 0; nf < 2; nf++) {
            int col = bx + nf * 16 + (l & 15);
            #pragma unroll
            for (int r = 0; r < 4; r++) {
                float h1 = acc1[m][nf][r], h2 = acc2[m][nf][r];
                float sil = h2 / (1.0f + __expf(-h2));
                C[(size_t)(row0 + r) * DFF + col] = f2bf(h1 * sil);
            }
        }
    }
}

// ---------------- per-expert top-CAP via bitonic sort ----------------
__global__ __launch_bounds__(1024) void expert_select_kernel(const float* __restrict__ wfull,
                                                             float* __restrict__ sw,
                                                             int* __restrict__ sidx,
                                                             int* __restrict__ slot) {
    __shared__ unsigned long long keys[2048];
    int e = blockIdx.x;
    int t = threadIdx.x;
    for (int i = t; i < 2048; i += 1024) {
        float w = wfull[i * 8 + e];
        unsigned int wb = __float_as_uint(w);
        keys[i] = ((unsigned long long)wb << 32) | (unsigned long long)(0xFFFFFFFFu - (unsigned int)i);
    }
    __syncthreads();
    for (int k = 2; k <= 2048; k <<= 1) {
        for (int j = k >> 1; j > 0; j >>= 1) {
            for (int i = t; i < 2048; i += 1024) {
                int ixj = i ^ j;
                if (ixj > i) {
                    bool desc = ((i & k) == 0);
                    unsigned long long a = keys[i], b = keys[ixj];
                    if ((a < b) == desc) { keys[i] = b; keys[ixj] = a; }
                }
            }
            __syncthreads();
        }
    }
    if (t < CAP) {
        unsigned long long kk = keys[t];
        float w = __uint_as_float((unsigned int)(kk >> 32));
        int idx = (int)(0xFFFFFFFFu - (unsigned int)(kk & 0xFFFFFFFFu));
        sw[e * CAP + t] = w;
        sidx[e * CAP + t] = idx;
        if (w > 0.f) slot[idx * 8 + e] = t;
    }
}

// ---------------- gather tokens -> bf16 ----------------
__global__ __launch_bounds__(256) void gather_tok_kernel(const float* __restrict__ hn,
                                                         const int* __restrict__ sidx,
                                                         const float* __restrict__ sw,
                                                         unsigned short* __restrict__ tok) {
    int ec = blockIdx.x;
    int tid = threadIdx.x;
    float w = sw[ec];
    int src = sidx[ec];
    const float* s = hn + (size_t)src * DMODEL;
    unsigned short* d = tok + (size_t)ec * DMODEL;
    for (int i = tid; i < DMODEL; i += 256) d[i] = (w > 0.f) ? f2bf(s[i]) : 0;
}

// ---------------- final combine ----------------
__global__ __launch_bounds__(256) void combine_kernel(const float* __restrict__ h,
                                                      const float* __restrict__ out_e,
                                                      const int* __restrict__ slot,
                                                      const float* __restrict__ wfull,
                                                      const float* __restrict__ gate_sum,
                                                      float* __restrict__ out) {
    int t = blockIdx.x;
    int tid = threadIdx.x;
    for (int d = tid; d < DMODEL; d += 256) {
        float acc = h[(size_t)t * DMODEL + d];
        #pragma unroll
        for (int e = 0; e < 8; e++) {
            int c = slot[t * 8 + e];
            if (c >= 0) acc += wfull[t * 8 + e] * out_e[((size_t)(e * CAP + c)) * DMODEL + d];
        }
        out[(size_t)t * DMODEL + d] = acc;
    }
    if (t == 0 && tid == 0) {
        float a = 0.f;
        #pragma unroll
        for (int e = 0; e < 8; e++) { float m = gate_sum[e] / (float)T_TOK; a += m * m; }
        out[(size_t)T_TOK * DMODEL] = 8.0f * a;
    }
}

extern "C" void kernel_launch(void* const* d_in, const int* in_sizes, int n_in,
                              void* d_out, int out_size, void* d_ws, size_t ws_size,
                              hipStream_t stream) {
    const float* x     = (const float*)d_in[0];
    const int*   gtm   = (const int*)d_in[2];
    const float* Wq    = (const float*)d_in[3];
    const float* Wk    = (const float*)d_in[4];
    const float* Wv    = (const float*)d_in[5];
    const float* Wo    = (const float*)d_in[6];
    const float* g1    = (const float*)d_in[7];
    const float* g2    = (const float*)d_in[8];
    const float* Wgate = (const float*)d_in[9];
    const float* W1    = (const float*)d_in[10];
    const float* W2    = (const float*)d_in[11];
    float* out = (float*)d_out;

    char* ws = (char*)d_ws;
    unsigned short* Qh   = (unsigned short*)(ws + 0);
    unsigned short* Ql   = (unsigned short*)(ws + 4194304);
    unsigned short* Kh   = (unsigned short*)(ws + 8388608);
    unsigned short* Kl   = (unsigned short*)(ws + 12582912);
    unsigned short* Vtb  = (unsigned short*)(ws + 16777216);
    unsigned short* act  = (unsigned short*)(ws + 0);           // MoE phase; Q/K dead
    unsigned short* xn   = (unsigned short*)(ws + 20971520);
    unsigned short* attno= (unsigned short*)(ws + 25165824);
    float* hb    = (float*)(ws + 29360128);
    float* hnb   = (float*)(ws + 37748736);
    float* oute  = (float*)(ws + 46137344);
    unsigned short* tok = (unsigned short*)(ws + 54525952);
    float* ropec = (float*)(ws + 58720256);
    float* ropes = (float*)(ws + 58851328);
    float* wfull = (float*)(ws + 58982400);
    int*   slot  = (int*)(ws + 59047936);
    float* sw    = (float*)(ws + 59113472);
    int*   sidx  = (int*)(ws + 59121664);
    float* gsum  = (float*)(ws + 59129856);
    int*   gidx  = (int*)(ws + 59131904);
    int*   gcnt  = (int*)(ws + 59133952);
    unsigned short* Kgh = (unsigned short*)(ws + 59140096);     // 512 KB
    unsigned short* Kgl = (unsigned short*)(ws + 59664384);     // 512 KB
    unsigned short* Vgt = (unsigned short*)(ws + 60188672);     // 512 KB

    rope_table_kernel<<<S_LEN, 32, 0, stream>>>(ropec, ropes, gsum);
    gscan_kernel<<<2, 1024, 0, stream>>>(gtm, gidx, gcnt);
    rmsnorm_kernel<<<T_TOK, 256, 0, stream>>>(x, g1, xn);

    gemm_qkv_rope<<<dim3(48, 16, 1), 256, 0, stream>>>(
        xn, Wq, Wk, Wv, ropec, ropes, Qh, Ql, Kh, Kl, Vtb);

    gather_gkv_kernel<<<32, 256, 0, stream>>>(Kh, Kl, Vtb, gidx, gcnt, Kgh, Kgl, Vgt);

    attn_mfma_kernel<<<dim3(16, 16, 2), 256, 0, stream>>>(
        Qh, Ql, Kh, Kl, Vtb, Kgh, Kgl, Vgt, gtm, gcnt, attno);

    attn_fixup_kernel<<<dim3(128, 16, 2), 256, 0, stream>>>(
        Qh, Ql, Kh, Kl, Vtb, gidx, gcnt, attno);

    // h = x + attno @ Wo  (f32 Wo read directly)
    gemm_bf32<1><<<dim3(32, 16, 1), 256, 0, stream>>>(
        attno, Wo, x, hb, 1024, 1024, 0, 0, 0);

    rmsnorm_gate_kernel<<<T_TOK, 256, 0, stream>>>(hb, g2, Wgate, hnb, wfull, slot, gsum);
    expert_select_kernel<<<NE, 1024, 0, stream>>>(wfull, sw, sidx, slot);
    gather_tok_kernel<<<NE * CAP, 256, 0, stream>>>(hnb, sidx, sw, tok);

    gemm_w1_fused<<<dim3(128, 8, 1), 256, 0, stream>>>(tok, W1, act);
    gemm_bf32<0><<<dim3(32, 2, 8), 256, 0, stream>>>(
        act, W2, nullptr, oute, 4096, 4096,
        (long long)CAP * DFF, (long long)DFF * 1024, (long long)CAP * 1024);

    combine_kernel<<<T_TOK, 256, 0, stream>>>(hb, oute, slot, wfull, gsum, out);
}

// Round 13
// 554.439 us; speedup vs baseline: 1.3240x; 1.3240x over previous
//
#include <hip/hip_runtime.h>
#include <hip/hip_bf16.h>
#include <math.h>

#define T_TOK 2048
#define DMODEL 1024
#define NH 16
#define HD 64
#define S_LEN 1024
#define NE 8
#define CAP 256
#define DFF 4096

typedef __attribute__((ext_vector_type(8))) short bf16x8;
typedef __attribute__((ext_vector_type(4))) float f32x4;

__device__ inline unsigned short f2bf(float f) {
    union { float f; unsigned int u; } x; x.f = f;
    unsigned int u = x.u;
    unsigned int r = (u + 0x7FFFu + ((u >> 16) & 1u)) >> 16;
    return (unsigned short)r;
}

__device__ inline float bf2f(unsigned short h) {
    union { unsigned int u; float f; } x; x.u = (unsigned int)h << 16; return x.f;
}

// packed f32x2 -> bf16x2 (RTNE); lo in low 16 bits
__device__ inline unsigned int pkbf(float lo, float hi) {
    __hip_bfloat162 h2 = __float22bfloat162_rn(make_float2(lo, hi));
    unsigned int r;
    __builtin_memcpy(&r, &h2, 4);
    return r;
}

__device__ inline void gload16(const void* g, void* l) {
    __builtin_amdgcn_global_load_lds(
        (const __attribute__((address_space(1))) unsigned int*)g,
        (__attribute__((address_space(3))) unsigned int*)l, 16, 0, 0);
}

// ---------------- RoPE table (+ gsum zero) ----------------
__global__ void rope_table_kernel(float* __restrict__ rc, float* __restrict__ rs,
                                  float* __restrict__ gsum) {
    int s = blockIdx.x;
    int i = threadIdx.x;
    float invf = powf(10000.0f, -(float)(2 * i) / 64.0f);
    float ang = (float)s * invf;
    rc[s * 32 + i] = cosf(ang);
    rs[s * 32 + i] = sinf(ang);
    if (blockIdx.x == 0 && threadIdx.x < 8) gsum[threadIdx.x] = 0.f;
}

// ---------------- global-token scan: packed indices + count per batch ----------------
__global__ __launch_bounds__(1024) void gscan_kernel(const int* __restrict__ gtm,
                                                     int* __restrict__ gidx,
                                                     int* __restrict__ gcnt) {
    __shared__ int ps[1024];
    int b = blockIdx.x, t = threadIdx.x;
    int f = gtm[b * 1024 + t] ? 1 : 0;
    ps[t] = f;
    __syncthreads();
    for (int off = 1; off < 1024; off <<= 1) {
        int v = (t >= off) ? ps[t - off] : 0;
        __syncthreads();
        ps[t] += v;
        __syncthreads();
    }
    if (f) {
        int pos = ps[t] - 1;
        if (pos < 128) gidx[b * 128 + pos] = t;
    }
    if (t == 1023) gcnt[b] = ps[1023] > 128 ? 128 : ps[1023];
}

// ---------------- RMSNorm (bf16 out) ----------------
__global__ __launch_bounds__(256) void rmsnorm_kernel(const float* __restrict__ x,
                                                      const float* __restrict__ g,
                                                      unsigned short* __restrict__ y) {
    __shared__ float red[256];
    int t = blockIdx.x;
    int tid = threadIdx.x;
    const float* xr = x + (size_t)t * DMODEL;
    float ss = 0.f;
    for (int d = tid; d < DMODEL; d += 256) { float v = xr[d]; ss += v * v; }
    red[tid] = ss; __syncthreads();
    for (int o = 128; o > 0; o >>= 1) { if (tid < o) red[tid] += red[tid + o]; __syncthreads(); }
    float scale = 1.0f / sqrtf(red[0] / (float)DMODEL + 1e-6f);
    unsigned short* yr = y + (size_t)t * DMODEL;
    for (int d = tid; d < DMODEL; d += 256) yr[d] = f2bf(g[d] * xr[d] * scale);
}

// ---------------- fused RMSNorm + gate (per token) ----------------
__global__ __launch_bounds__(256) void rmsnorm_gate_kernel(const float* __restrict__ x,
                                                           const float* __restrict__ g,
                                                           const float* __restrict__ Wgate,
                                                           float* __restrict__ y,
                                                           float* __restrict__ wfull,
                                                           int* __restrict__ slot,
                                                           float* __restrict__ gate_sum) {
    __shared__ float red[256];
    __shared__ float lg[8];
    int t = blockIdx.x, tid = threadIdx.x;
    const float* xr = x + (size_t)t * DMODEL;
    float xv[4]; float ss = 0.f;
    #pragma unroll
    for (int i = 0; i < 4; i++) { xv[i] = xr[tid + i * 256]; ss += xv[i] * xv[i]; }
    red[tid] = ss; __syncthreads();
    for (int o = 128; o > 0; o >>= 1) { if (tid < o) red[tid] += red[tid + o]; __syncthreads(); }
    float scale = 1.0f / sqrtf(red[0] / (float)DMODEL + 1e-6f);
    float part[8] = {};
    float* yr = y + (size_t)t * DMODEL;
    #pragma unroll
    for (int i = 0; i < 4; i++) {
        int d = tid + i * 256;
        float yv = g[d] * xv[i] * scale;
        yr[d] = yv;
        const float* wg = Wgate + d * 8;
        #pragma unroll
        for (int e = 0; e < 8; e++) part[e] += yv * wg[e];
    }
    __syncthreads();
    for (int e = 0; e < 8; e++) {
        red[tid] = part[e]; __syncthreads();
        for (int o = 128; o > 0; o >>= 1) { if (tid < o) red[tid] += red[tid + o]; __syncthreads(); }
        if (tid == 0) lg[e] = red[0];
        __syncthreads();
    }
    if (tid == 0) {
        float mx = lg[0];
        #pragma unroll
        for (int e = 1; e < 8; e++) mx = fmaxf(mx, lg[e]);
        float pr[8]; float s = 0.f;
        #pragma unroll
        for (int e = 0; e < 8; e++) { pr[e] = __expf(lg[e] - mx); s += pr[e]; }
        float inv = 1.0f / s;
        int e1 = 0; float v1 = -1.f;
        #pragma unroll
        for (int e = 0; e < 8; e++) {
            pr[e] *= inv;
            atomicAdd(&gate_sum[e], pr[e]);
            if (pr[e] > v1) { v1 = pr[e]; e1 = e; }
        }
        int e2 = -1; float v2 = -1.f;
        #pragma unroll
        for (int e = 0; e < 8; e++) {
            if (e == e1) continue;
            if (pr[e] > v2) { v2 = pr[e]; e2 = e; }
        }
        #pragma unroll
        for (int e = 0; e < 8; e++) {
            wfull[t * 8 + e] = (e == e1) ? v1 : (e == e2) ? v2 : 0.f;
            slot[t * 8 + e] = -1;
        }
    }
}

// ---------------- fused QKV GEMM + RoPE + hi/lo + V-transpose (B reg-prefetch) ----------------
__global__ __launch_bounds__(256) void gemm_qkv_rope(const unsigned short* __restrict__ xn,
                                                     const float* __restrict__ Wq,
                                                     const float* __restrict__ Wk,
                                                     const float* __restrict__ Wv,
                                                     const float* __restrict__ rc,
                                                     const float* __restrict__ rs,
                                                     unsigned short* __restrict__ Qh,
                                                     unsigned short* __restrict__ Ql,
                                                     unsigned short* __restrict__ Kh,
                                                     unsigned short* __restrict__ Kl,
                                                     unsigned short* __restrict__ Vtb) {
    __shared__ unsigned short As[128 * 64];
    __shared__ unsigned int Bp[64 * 32];
    const int mat = blockIdx.x >> 4;
    const int h = blockIdx.x & 15;
    const float* B = ((mat == 0) ? Wq : (mat == 1) ? Wk : Wv) + h * 64;
    const int by = blockIdx.y * 128;
    const int tid = threadIdx.x, l = tid & 63, wid = tid >> 6;
    const int g = l >> 4;
    const int kp = tid >> 3;
    const int nc = tid & 7;
    const int chunk = kp >> 2, within = kp & 3;

    f32x4 acc[2][4] = {};

    const float* Brow = B + (size_t)(2 * kp) * 1024 + nc * 8;
    float4 a0 = *(const float4*)(Brow);
    float4 a1 = *(const float4*)(Brow + 4);
    float4 b0 = *(const float4*)(Brow + 1024);
    float4 b1 = *(const float4*)(Brow + 1028);

    for (int k0 = 0; k0 < 1024; k0 += 64) {
        #pragma unroll
        for (int i = 0; i < 4; i++) {
            int c = i * 256 + tid;
            int row = c >> 3, sl = c & 7, gs = sl ^ (row & 7);
            gload16(xn + (size_t)(by + row) * 1024 + k0 + gs * 8, &As[c * 8]);
        }
        unsigned int p[8];
        p[0] = pkbf(a0.x, b0.x); p[1] = pkbf(a0.y, b0.y);
        p[2] = pkbf(a0.z, b0.z); p[3] = pkbf(a0.w, b0.w);
        p[4] = pkbf(a1.x, b1.x); p[5] = pkbf(a1.y, b1.y);
        p[6] = pkbf(a1.z, b1.z); p[7] = pkbf(a1.w, b1.w);
        #pragma unroll
        for (int i = 0; i < 8; i++) {
            int n_loc = nc * 8 + i;
            int idx = n_loc * 32 + ((chunk ^ (n_loc & 7)) << 2) + within;
            Bp[idx] = p[i];
        }
        __syncthreads();
        if (k0 + 64 < 1024) {
            const float* Bn = B + (size_t)(k0 + 64 + 2 * kp) * 1024 + nc * 8;
            a0 = *(const float4*)(Bn);
            a1 = *(const float4*)(Bn + 4);
            b0 = *(const float4*)(Bn + 1024);
            b1 = *(const float4*)(Bn + 1028);
        }
        #pragma unroll
        for (int ks = 0; ks < 2; ks++) {
            bf16x8 af[2];
            #pragma unroll
            for (int m = 0; m < 2; m++) {
                int row = wid * 32 + m * 16 + (l & 15);
                int sl = (ks * 4 + g) ^ (row & 7);
                af[m] = *(const bf16x8*)&As[row * 64 + sl * 8];
            }
            #pragma unroll
            for (int nf = 0; nf < 4; nf++) {
                int n_loc = nf * 16 + (l & 15);
                int base = n_loc * 32 + (((ks * 4 + g) ^ (n_loc & 7)) << 2);
                bf16x8 bfr = *(const bf16x8*)&Bp[base];
                #pragma unroll
                for (int m = 0; m < 2; m++)
                    acc[m][nf] = __builtin_amdgcn_mfma_f32_16x16x32_bf16(af[m], bfr, acc[m][nf], 0, 0, 0);
            }
        }
        __syncthreads();
    }

    if (mat < 2) {
        unsigned short* Dh = (mat == 0) ? Qh : Kh;
        unsigned short* Dl = (mat == 0) ? Ql : Kl;
        float scale = (mat == 0) ? 0.125f : 1.0f;
        #pragma unroll
        for (int m = 0; m < 2; m++)
            #pragma unroll
            for (int r = 0; r < 4; r++) {
                int t = by + wid * 32 + m * 16 + g * 4 + r;
                int b = t >> 10, s = t & 1023;
                size_t ob = ((size_t)(b * 16 + h) * 1024 + s) * 64;
                #pragma unroll
                for (int pr = 0; pr < 2; pr++) {
                    int i = pr * 16 + (l & 15);
                    float c = rc[s * 32 + i], sn = rs[s * 32 + i];
                    float a = acc[m][pr][r], bb = acc[m][pr + 2][r];
                    float v0 = (a * c - bb * sn) * scale;
                    float v1 = (bb * c + a * sn) * scale;
                    unsigned short h0 = f2bf(v0), h1 = f2bf(v1);
                    Dh[ob + i] = h0;      Dl[ob + i] = f2bf(v0 - bf2f(h0));
                    Dh[ob + i + 32] = h1; Dl[ob + i + 32] = f2bf(v1 - bf2f(h1));
                }
            }
    } else {
        #pragma unroll
        for (int m = 0; m < 2; m++) {
            int t0 = by + wid * 32 + m * 16 + g * 4;
            int b = t0 >> 10, s0 = t0 & 1023;
            #pragma unroll
            for (int nf = 0; nf < 4; nf++) {
                int d = nf * 16 + (l & 15);
                unsigned short tmp[4];
                #pragma unroll
                for (int r = 0; r < 4; r++) tmp[r] = f2bf(acc[m][nf][r]);
                *(uint2*)&Vtb[((size_t)(b * 16 + h) * 64 + d) * 1024 + s0] = *(uint2*)tmp;
            }
        }
    }
}

// ---------------- gather global-token Q/K/V into packed tiles ----------------
__global__ __launch_bounds__(256) void gather_gkv_kernel(const unsigned short* __restrict__ Qh,
                                                         const unsigned short* __restrict__ Ql,
                                                         const unsigned short* __restrict__ Kh,
                                                         const unsigned short* __restrict__ Kl,
                                                         const unsigned short* __restrict__ Vtb,
                                                         const int* __restrict__ gidx,
                                                         const int* __restrict__ gcnt,
                                                         unsigned short* __restrict__ Qgh,
                                                         unsigned short* __restrict__ Qgl,
                                                         unsigned short* __restrict__ Kgh,
                                                         unsigned short* __restrict__ Kgl,
                                                         unsigned short* __restrict__ Vgt) {
    int bh = blockIdx.x;
    int b = bh >> 4;
    int cnt = gcnt[b];
    int tid = threadIdx.x;
    for (int i = tid; i < 128 * 8; i += 256) {
        int slot = i >> 3, c8 = (i & 7) * 8;
        size_t dst = ((size_t)bh * 128 + slot) * 64 + c8;
        if (slot < cnt) {
            int idx = gidx[b * 128 + slot];
            size_t src = ((size_t)bh * 1024 + idx) * 64 + c8;
            *(uint4*)(Qgh + dst) = *(const uint4*)(Qh + src);
            *(uint4*)(Qgl + dst) = *(const uint4*)(Ql + src);
            *(uint4*)(Kgh + dst) = *(const uint4*)(Kh + src);
            *(uint4*)(Kgl + dst) = *(const uint4*)(Kl + src);
        } else {
            uint4 z = {0, 0, 0, 0};
            *(uint4*)(Qgh + dst) = z;
            *(uint4*)(Qgl + dst) = z;
            *(uint4*)(Kgh + dst) = z;
            *(uint4*)(Kgl + dst) = z;
        }
    }
    for (int i = tid; i < 64 * 16; i += 256) {
        int d = i >> 4, s8 = (i & 15) * 8;
        unsigned short tmp[8];
        #pragma unroll
        for (int u = 0; u < 8; u++) {
            int slot = s8 + u;
            tmp[u] = (slot < cnt) ? Vtb[((size_t)bh * 64 + d) * 1024 + gidx[b * 128 + slot]]
                                  : (unsigned short)0;
        }
        *(uint4*)(Vgt + ((size_t)bh * 64 + d) * 128 + s8) = *(uint4*)tmp;
    }
}

// ---------------- sparse flash attention: window tiles + gathered global tiles ----------------
__global__ __launch_bounds__(256) void attn_mfma_kernel(const unsigned short* __restrict__ Qh,
                                                        const unsigned short* __restrict__ Ql,
                                                        const unsigned short* __restrict__ Kh,
                                                        const unsigned short* __restrict__ Kl,
                                                        const unsigned short* __restrict__ Vtb,
                                                        const unsigned short* __restrict__ Kgh,
                                                        const unsigned short* __restrict__ Kgl,
                                                        const unsigned short* __restrict__ Vgt,
                                                        const int* __restrict__ gtm,
                                                        const int* __restrict__ gcnt,
                                                        unsigned short* __restrict__ o) {
    __shared__ unsigned short Ksh[2][64 * 64];
    __shared__ unsigned short Ksl[2][64 * 64];
    __shared__ unsigned short Vs[2][64 * 64];
    __shared__ unsigned short Pl[4][16 * 64];
    const int qt = blockIdx.x, h = blockIdx.y, b = blockIdx.z;
    const int bh = b * 16 + h;
    const int tid = threadIdx.x, l = tid & 63, w = tid >> 6;
    const int q0 = qt * 64 + w * 16;
    const int jt_lo = (qt >= 4) ? (qt - 4) : 0;
    const int nwin = qt - jt_lo + 1;
    const int ntiles = nwin + 2;
    const int cnt = gcnt[b];
    const unsigned short* Qhb = Qh + (size_t)bh * 1024 * 64;
    const unsigned short* Qlb = Ql + (size_t)bh * 1024 * 64;
    const unsigned short* Khb = Kh + (size_t)bh * 1024 * 64;
    const unsigned short* Klb = Kl + (size_t)bh * 1024 * 64;
    const unsigned short* Vbh = Vtb + (size_t)bh * 64 * 1024;
    const unsigned short* Kghb = Kgh + (size_t)bh * 128 * 64;
    const unsigned short* Kglb = Kgl + (size_t)bh * 128 * 64;
    const unsigned short* Vgtb = Vgt + (size_t)bh * 64 * 128;
    const int* gb = gtm + b * 1024;

    bf16x8 afh[2], afl[2];
    #pragma unroll
    for (int ks = 0; ks < 2; ks++) {
        size_t off = (size_t)(q0 + (l & 15)) * 64 + ks * 32 + (l >> 4) * 8;
        afh[ks] = *(const bf16x8*)(Qhb + off);
        afl[ks] = *(const bf16x8*)(Qlb + off);
    }

    f32x4 acc_o[4] = {};
    float m_run[4], l_run[4];
    #pragma unroll
    for (int r = 0; r < 4; r++) { m_run[r] = -1e30f; l_run[r] = 0.f; }

    auto STAGE = [&](int ti, int buf) {
        if (ti < nwin) {
            int j0s = (jt_lo + ti) * 64;
            #pragma unroll
            for (int i = 0; i < 2; i++) {
                int c = i * 256 + tid, row = c >> 3, sl = c & 7, gs = sl ^ (row & 7);
                gload16(Khb + (size_t)(j0s + row) * 64 + gs * 8, &Ksh[buf][c * 8]);
                gload16(Klb + (size_t)(j0s + row) * 64 + gs * 8, &Ksl[buf][c * 8]);
                gload16(Vbh + (size_t)row * 1024 + j0s + gs * 8, &Vs[buf][c * 8]);
            }
        } else {
            int g0 = (ti - nwin) * 64;
            #pragma unroll
            for (int i = 0; i < 2; i++) {
                int c = i * 256 + tid, row = c >> 3, sl = c & 7, gs = sl ^ (row & 7);
                gload16(Kghb + (size_t)(g0 + row) * 64 + gs * 8, &Ksh[buf][c * 8]);
                gload16(Kglb + (size_t)(g0 + row) * 64 + gs * 8, &Ksl[buf][c * 8]);
                gload16(Vgtb + (size_t)row * 128 + g0 + gs * 8, &Vs[buf][c * 8]);
            }
        }
    };

    STAGE(0, 0);
    int cur = 0;

    for (int ti = 0; ti < ntiles; ti++) {
        __syncthreads();
        if (ti + 1 < ntiles) STAGE(ti + 1, cur ^ 1);

        f32x4 sv[4] = {};
        __builtin_amdgcn_s_setprio(1);
        #pragma unroll
        for (int n = 0; n < 4; n++) {
            #pragma unroll
            for (int ks = 0; ks < 2; ks++) {
                int row = n * 16 + (l & 15);
                int sl = (ks * 4 + (l >> 4)) ^ (row & 7);
                bf16x8 khf = *(const bf16x8*)&Ksh[cur][row * 64 + sl * 8];
                bf16x8 klf = *(const bf16x8*)&Ksl[cur][row * 64 + sl * 8];
                sv[n] = __builtin_amdgcn_mfma_f32_16x16x32_bf16(afl[ks], khf, sv[n], 0, 0, 0);
                sv[n] = __builtin_amdgcn_mfma_f32_16x16x32_bf16(afh[ks], klf, sv[n], 0, 0, 0);
                sv[n] = __builtin_amdgcn_mfma_f32_16x16x32_bf16(afh[ks], khf, sv[n], 0, 0, 0);
            }
        }
        __builtin_amdgcn_s_setprio(0);

        if (ti < nwin) {
            int j0 = (jt_lo + ti) * 64;
            int gk[4];
            #pragma unroll
            for (int n = 0; n < 4; n++) gk[n] = gb[j0 + n * 16 + (l & 15)];
            #pragma unroll
            for (int n = 0; n < 4; n++)
                #pragma unroll
                for (int r = 0; r < 4; r++) {
                    int q = q0 + (l >> 4) * 4 + r;
                    int k = j0 + n * 16 + (l & 15);
                    bool allowed = (k <= q) && (q - k < 256) && !gk[n];
                    if (!allowed) sv[n][r] = -1e30f;
                }
        } else {
            int s0 = (ti - nwin) * 64;
            #pragma unroll
            for (int n = 0; n < 4; n++) {
                int slot = s0 + n * 16 + (l & 15);
                bool allowed = slot < cnt;
                #pragma unroll
                for (int r = 0; r < 4; r++)
                    if (!allowed) sv[n][r] = -1e30f;
            }
        }

        {
            float tm[4], corr[4], rsum[4];
            #pragma unroll
            for (int r = 0; r < 4; r++)
                tm[r] = fmaxf(fmaxf(sv[0][r], sv[1][r]), fmaxf(sv[2][r], sv[3][r]));
            #pragma unroll
            for (int wd = 1; wd <= 8; wd <<= 1)
                #pragma unroll
                for (int r = 0; r < 4; r++) tm[r] = fmaxf(tm[r], __shfl_xor(tm[r], wd, 64));
            #pragma unroll
            for (int r = 0; r < 4; r++) {
                float mn = fmaxf(m_run[r], tm[r]);
                corr[r] = __expf(m_run[r] - mn);
                m_run[r] = mn;
                rsum[r] = 0.f;
            }
            #pragma unroll
            for (int n = 0; n < 4; n++)
                #pragma unroll
                for (int r = 0; r < 4; r++) {
                    float p = __expf(sv[n][r] - m_run[r]);
                    sv[n][r] = p;
                    rsum[r] += p;
                }
            #pragma unroll
            for (int wd = 1; wd <= 8; wd <<= 1)
                #pragma unroll
                for (int r = 0; r < 4; r++) rsum[r] += __shfl_xor(rsum[r], wd, 64);
            #pragma unroll
            for (int r = 0; r < 4; r++) l_run[r] = l_run[r] * corr[r] + rsum[r];
            #pragma unroll
            for (int nd = 0; nd < 4; nd++)
                #pragma unroll
                for (int r = 0; r < 4; r++) acc_o[nd][r] *= corr[r];
            #pragma unroll
            for (int n = 0; n < 4; n++)
                #pragma unroll
                for (int r = 0; r < 4; r++) {
                    int qr = (l >> 4) * 4 + r;
                    int kc = n * 16 + (l & 15);
                    int byte = (qr * 128 + kc * 2) ^ ((qr & 7) << 4);
                    Pl[w][byte >> 1] = f2bf(sv[n][r]);
                }
        }

        asm volatile("s_waitcnt lgkmcnt(0)" ::: "memory");
        __builtin_amdgcn_sched_barrier(0);

        __builtin_amdgcn_s_setprio(1);
        #pragma unroll
        for (int ks = 0; ks < 2; ks++) {
            int prow = l & 15;
            int psl = (ks * 4 + (l >> 4)) ^ (prow & 7);
            bf16x8 pa = *(const bf16x8*)&Pl[w][prow * 64 + psl * 8];
            #pragma unroll
            for (int nd = 0; nd < 4; nd++) {
                int row = nd * 16 + (l & 15);
                int sl = (ks * 4 + (l >> 4)) ^ (row & 7);
                bf16x8 vf = *(const bf16x8*)&Vs[cur][row * 64 + sl * 8];
                acc_o[nd] = __builtin_amdgcn_mfma_f32_16x16x32_bf16(pa, vf, acc_o[nd], 0, 0, 0);
            }
        }
        __builtin_amdgcn_s_setprio(0);
        cur ^= 1;
    }

    #pragma unroll
    for (int r = 0; r < 4; r++) {
        float inv = 1.0f / l_run[r];
        int t_ = b * 1024 + q0 + (l >> 4) * 4 + r;
        #pragma unroll
        for (int nd = 0; nd < 4; nd++) {
            int col = h * 64 + nd * 16 + (l & 15);
            o[(size_t)t_ * 1024 + col] = f2bf(acc_o[nd][r] * inv);
        }
    }
}

// ---------------- dense flash attention for gathered global-q rows (MFMA) ----------------
__global__ __launch_bounds__(256) void attn_gq_kernel(const unsigned short* __restrict__ Qgh,
                                                      const unsigned short* __restrict__ Qgl,
                                                      const unsigned short* __restrict__ Kh,
                                                      const unsigned short* __restrict__ Kl,
                                                      const unsigned short* __restrict__ Vtb,
                                                      const int* __restrict__ gidx,
                                                      const int* __restrict__ gcnt,
                                                      unsigned short* __restrict__ o) {
    __shared__ unsigned short Ksh[2][64 * 64];
    __shared__ unsigned short Ksl[2][64 * 64];
    __shared__ unsigned short Vs[2][64 * 64];
    __shared__ unsigned short Pl[4][16 * 64];
    const int qt = blockIdx.x, h = blockIdx.y, b = blockIdx.z;
    const int bh = b * 16 + h;
    const int cnt = gcnt[b];
    if (qt * 64 >= cnt) return;
    const int tid = threadIdx.x, l = tid & 63, w = tid >> 6;
    const int q0 = qt * 64 + w * 16;   // slot base
    const unsigned short* Qhb = Qgh + (size_t)bh * 128 * 64;
    const unsigned short* Qlb = Qgl + (size_t)bh * 128 * 64;
    const unsigned short* Khb = Kh + (size_t)bh * 1024 * 64;
    const unsigned short* Klb = Kl + (size_t)bh * 1024 * 64;
    const unsigned short* Vbh = Vtb + (size_t)bh * 64 * 1024;

    bf16x8 afh[2], afl[2];
    #pragma unroll
    for (int ks = 0; ks < 2; ks++) {
        size_t off = (size_t)(q0 + (l & 15)) * 64 + ks * 32 + (l >> 4) * 8;
        afh[ks] = *(const bf16x8*)(Qhb + off);
        afl[ks] = *(const bf16x8*)(Qlb + off);
    }

    f32x4 acc_o[4] = {};
    float m_run[4], l_run[4];
    #pragma unroll
    for (int r = 0; r < 4; r++) { m_run[r] = -1e30f; l_run[r] = 0.f; }

    // prologue: stage tile 0
    #pragma unroll
    for (int i = 0; i < 2; i++) {
        int c = i * 256 + tid, row = c >> 3, sl = c & 7, gs = sl ^ (row & 7);
        gload16(Khb + (size_t)row * 64 + gs * 8, &Ksh[0][c * 8]);
        gload16(Klb + (size_t)row * 64 + gs * 8, &Ksl[0][c * 8]);
        gload16(Vbh + (size_t)row * 1024 + gs * 8, &Vs[0][c * 8]);
    }
    int cur = 0;

    for (int jt = 0; jt < 16; jt++) {
        __syncthreads();
        if (jt < 15) {
            int jn = (jt + 1) * 64, nb = cur ^ 1;
            #pragma unroll
            for (int i = 0; i < 2; i++) {
                int c = i * 256 + tid, row = c >> 3, sl = c & 7, gs = sl ^ (row & 7);
                gload16(Khb + (size_t)(jn + row) * 64 + gs * 8, &Ksh[nb][c * 8]);
                gload16(Klb + (size_t)(jn + row) * 64 + gs * 8, &Ksl[nb][c * 8]);
                gload16(Vbh + (size_t)row * 1024 + jn + gs * 8, &Vs[nb][c * 8]);
            }
        }

        f32x4 sv[4] = {};
        __builtin_amdgcn_s_setprio(1);
        #pragma unroll
        for (int n = 0; n < 4; n++) {
            #pragma unroll
            for (int ks = 0; ks < 2; ks++) {
                int row = n * 16 + (l & 15);
                int sl = (ks * 4 + (l >> 4)) ^ (row & 7);
                bf16x8 khf = *(const bf16x8*)&Ksh[cur][row * 64 + sl * 8];
                bf16x8 klf = *(const bf16x8*)&Ksl[cur][row * 64 + sl * 8];
                sv[n] = __builtin_amdgcn_mfma_f32_16x16x32_bf16(afl[ks], khf, sv[n], 0, 0, 0);
                sv[n] = __builtin_amdgcn_mfma_f32_16x16x32_bf16(afh[ks], klf, sv[n], 0, 0, 0);
                sv[n] = __builtin_amdgcn_mfma_f32_16x16x32_bf16(afh[ks], khf, sv[n], 0, 0, 0);
            }
        }
        __builtin_amdgcn_s_setprio(0);

        // no masking: global-q rows attend to every column
        {
            float tm[4], corr[4], rsum[4];
            #pragma unroll
            for (int r = 0; r < 4; r++)
                tm[r] = fmaxf(fmaxf(sv[0][r], sv[1][r]), fmaxf(sv[2][r], sv[3][r]));
            #pragma unroll
            for (int wd = 1; wd <= 8; wd <<= 1)
                #pragma unroll
                for (int r = 0; r < 4; r++) tm[r] = fmaxf(tm[r], __shfl_xor(tm[r], wd, 64));
            #pragma unroll
            for (int r = 0; r < 4; r++) {
                float mn = fmaxf(m_run[r], tm[r]);
                corr[r] = __expf(m_run[r] - mn);
                m_run[r] = mn;
                rsum[r] = 0.f;
            }
            #pragma unroll
            for (int n = 0; n < 4; n++)
                #pragma unroll
                for (int r = 0; r < 4; r++) {
                    float p = __expf(sv[n][r] - m_run[r]);
                    sv[n][r] = p;
                    rsum[r] += p;
                }
            #pragma unroll
            for (int wd = 1; wd <= 8; wd <<= 1)
                #pragma unroll
                for (int r = 0; r < 4; r++) rsum[r] += __shfl_xor(rsum[r], wd, 64);
            #pragma unroll
            for (int r = 0; r < 4; r++) l_run[r] = l_run[r] * corr[r] + rsum[r];
            #pragma unroll
            for (int nd = 0; nd < 4; nd++)
                #pragma unroll
                for (int r = 0; r < 4; r++) acc_o[nd][r] *= corr[r];
            #pragma unroll
            for (int n = 0; n < 4; n++)
                #pragma unroll
                for (int r = 0; r < 4; r++) {
                    int qr = (l >> 4) * 4 + r;
                    int kc = n * 16 + (l & 15);
                    int byte = (qr * 128 + kc * 2) ^ ((qr & 7) << 4);
                    Pl[w][byte >> 1] = f2bf(sv[n][r]);
                }
        }

        asm volatile("s_waitcnt lgkmcnt(0)" ::: "memory");
        __builtin_amdgcn_sched_barrier(0);

        __builtin_amdgcn_s_setprio(1);
        #pragma unroll
        for (int ks = 0; ks < 2; ks++) {
            int prow = l & 15;
            int psl = (ks * 4 + (l >> 4)) ^ (prow & 7);
            bf16x8 pa = *(const bf16x8*)&Pl[w][prow * 64 + psl * 8];
            #pragma unroll
            for (int nd = 0; nd < 4; nd++) {
                int row = nd * 16 + (l & 15);
                int sl = (ks * 4 + (l >> 4)) ^ (row & 7);
                bf16x8 vf = *(const bf16x8*)&Vs[cur][row * 64 + sl * 8];
                acc_o[nd] = __builtin_amdgcn_mfma_f32_16x16x32_bf16(pa, vf, acc_o[nd], 0, 0, 0);
            }
        }
        __builtin_amdgcn_s_setprio(0);
        cur ^= 1;
    }

    #pragma unroll
    for (int r = 0; r < 4; r++) {
        int slot_r = q0 + (l >> 4) * 4 + r;
        if (slot_r < cnt) {
            int t_ = b * 1024 + gidx[b * 128 + slot_r];
            float inv = 1.0f / l_run[r];
            #pragma unroll
            for (int nd = 0; nd < 4; nd++) {
                int col = h * 64 + nd * 16 + (l & 15);
                o[(size_t)t_ * 1024 + col] = f2bf(acc_o[nd][r] * inv);
            }
        }
    }
}

// ---------------- generic fused GEMM: C(f32) = A(bf16) @ B(f32), B reg-prefetch ----------------
template <int RES>
__global__ __launch_bounds__(256) void gemm_bf32(const unsigned short* __restrict__ A,
                                                 const float* __restrict__ B,
                                                 const float* __restrict__ Rr,
                                                 float* __restrict__ C,
                                                 int K, int lda,
                                                 long long sA, long long sB, long long sC) {
    __shared__ unsigned short As[128 * 64];
    __shared__ unsigned int Bp[32 * 32];
    A += (long long)blockIdx.z * sA + (long long)blockIdx.y * 128 * lda;
    B += (long long)blockIdx.z * sB;
    C += (long long)blockIdx.z * sC + (long long)blockIdx.y * 128 * 1024;
    const float* Rp = RES ? (Rr + (long long)blockIdx.y * 128 * 1024) : nullptr;
    const int bx = blockIdx.x * 32;
    const int tid = threadIdx.x, l = tid & 63, wid = tid >> 6;
    const int g = l >> 4;
    const int kp = tid >> 3;
    const int nc = tid & 7;
    const int chunk = kp >> 2, within = kp & 3;

    f32x4 acc[2][2] = {};

    const float* Brow = B + (size_t)(2 * kp) * 1024 + bx + nc * 4;
    float4 a0 = *(const float4*)(Brow);
    float4 a1 = *(const float4*)(Brow + 1024);

    for (int k0 = 0; k0 < K; k0 += 64) {
        #pragma unroll
        for (int i = 0; i < 4; i++) {
            int c = i * 256 + tid;
            int row = c >> 3, sl = c & 7, gs = sl ^ (row & 7);
            gload16(A + (size_t)row * lda + k0 + gs * 8, &As[c * 8]);
        }
        unsigned int p1[4];
        p1[0] = pkbf(a0.x, a1.x); p1[1] = pkbf(a0.y, a1.y);
        p1[2] = pkbf(a0.z, a1.z); p1[3] = pkbf(a0.w, a1.w);
        #pragma unroll
        for (int i = 0; i < 4; i++) {
            int n_loc = nc * 4 + i;
            int idx = n_loc * 32 + ((chunk ^ (n_loc & 7)) << 2) + within;
            Bp[idx] = p1[i];
        }
        __syncthreads();
        if (k0 + 64 < K) {
            const float* Bn = B + (size_t)(k0 + 64 + 2 * kp) * 1024 + bx + nc * 4;
            a0 = *(const float4*)(Bn);
            a1 = *(const float4*)(Bn + 1024);
        }
        #pragma unroll
        for (int ks = 0; ks < 2; ks++) {
            bf16x8 af[2];
            #pragma unroll
            for (int m = 0; m < 2; m++) {
                int row = wid * 32 + m * 16 + (l & 15);
                int sl = (ks * 4 + g) ^ (row & 7);
                af[m] = *(const bf16x8*)&As[row * 64 + sl * 8];
            }
            #pragma unroll
            for (int nf = 0; nf < 2; nf++) {
                int n_loc = nf * 16 + (l & 15);
                int base = n_loc * 32 + (((ks * 4 + g) ^ (n_loc & 7)) << 2);
                bf16x8 bfr = *(const bf16x8*)&Bp[base];
                #pragma unroll
                for (int m = 0; m < 2; m++)
                    acc[m][nf] = __builtin_amdgcn_mfma_f32_16x16x32_bf16(af[m], bfr, acc[m][nf], 0, 0, 0);
            }
        }
        __syncthreads();
    }
    #pragma unroll
    for (int m = 0; m < 2; m++) {
        int row0 = wid * 32 + m * 16 + g * 4;
        #pragma unroll
        for (int nf = 0; nf < 2; nf++) {
            int col = bx + nf * 16 + (l & 15);
            #pragma unroll
            for (int r = 0; r < 4; r++) {
                size_t idx = (size_t)(row0 + r) * 1024 + col;
                float v = acc[m][nf][r];
                if (RES) v += Rp[idx];
                C[idx] = v;
            }
        }
    }
}

// ---------------- fused MoE W1 GEMM + SwiGLU (B reg-prefetch) ----------------
__global__ __launch_bounds__(256) void gemm_w1_fused(const unsigned short* __restrict__ tok,
                                                     const float* __restrict__ W1,
                                                     unsigned short* __restrict__ act) {
    __shared__ unsigned short As[256 * 64];
    __shared__ unsigned int B1p[32 * 32];
    __shared__ unsigned int B2p[32 * 32];
    const int e = blockIdx.y;
    const int bx = blockIdx.x * 32;
    const unsigned short* A = tok + (size_t)e * CAP * DMODEL;
    const float* B = W1 + (size_t)e * DMODEL * (2 * DFF);
    unsigned short* C = act + (size_t)e * CAP * DFF;
    const int tid = threadIdx.x, l = tid & 63, wid = tid >> 6;
    const int g = l >> 4;
    const int kp = tid >> 3;
    const int nc = tid & 7;
    const int chunk = kp >> 2, within = kp & 3;

    f32x4 acc1[4][2] = {};
    f32x4 acc2[4][2] = {};

    const float* Brow = B + (size_t)(2 * kp) * 8192 + bx + nc * 4;
    float4 a0 = *(const float4*)(Brow);
    float4 a1 = *(const float4*)(Brow + 8192);
    float4 c0 = *(const float4*)(Brow + 4096);
    float4 c1 = *(const float4*)(Brow + 4096 + 8192);

    for (int k0 = 0; k0 < DMODEL; k0 += 64) {
        #pragma unroll
        for (int i = 0; i < 8; i++) {
            int c = i * 256 + tid;
            int row = c >> 3, sl = c & 7, gs = sl ^ (row & 7);
            gload16(A + (size_t)row * DMODEL + k0 + gs * 8, &As[c * 8]);
        }
        unsigned int p1[4], p2[4];
        p1[0] = pkbf(a0.x, a1.x); p1[1] = pkbf(a0.y, a1.y);
        p1[2] = pkbf(a0.z, a1.z); p1[3] = pkbf(a0.w, a1.w);
        p2[0] = pkbf(c0.x, c1.x); p2[1] = pkbf(c0.y, c1.y);
        p2[2] = pkbf(c0.z, c1.z); p2[3] = pkbf(c0.w, c1.w);
        #pragma unroll
        for (int i = 0; i < 4; i++) {
            int n_loc = nc * 4 + i;
            int idx = n_loc * 32 + ((chunk ^ (n_loc & 7)) << 2) + within;
            B1p[idx] = p1[i];
            B2p[idx] = p2[i];
        }
        __syncthreads();
        if (k0 + 64 < DMODEL) {
            const float* Bn = B + (size_t)(k0 + 64 + 2 * kp) * 8192 + bx + nc * 4;
            a0 = *(const float4*)(Bn);
            a1 = *(const float4*)(Bn + 8192);
            c0 = *(const float4*)(Bn + 4096);
            c1 = *(const float4*)(Bn + 4096 + 8192);
        }
        #pragma unroll
        for (int ks = 0; ks < 2; ks++) {
            bf16x8 af[4];
            #pragma unroll
            for (int m = 0; m < 4; m++) {
                int row = wid * 64 + m * 16 + (l & 15);
                int sl = (ks * 4 + g) ^ (row & 7);
                af[m] = *(const bf16x8*)&As[row * 64 + sl * 8];
            }
            #pragma unroll
            for (int nf = 0; nf < 2; nf++) {
                int n_loc = nf * 16 + (l & 15);
                int base = n_loc * 32 + (((ks * 4 + g) ^ (n_loc & 7)) << 2);
                bf16x8 b1 = *(const bf16x8*)&B1p[base];
                bf16x8 b2 = *(const bf16x8*)&B2p[base];
                #pragma unroll
                for (int m = 0; m < 4; m++) {
                    acc1[m][nf] = __builtin_amdgcn_mfma_f32_16x16x32_bf16(af[m], b1, acc1[m][nf], 0, 0, 0);
                    acc2[m][nf] = __builtin_amdgcn_mfma_f32_16x16x32_bf16(af[m], b2, acc2[m][nf], 0, 0, 0);
                }
            }
        }
        __syncthreads();
    }
    #pragma unroll
    for (int m = 0; m < 4; m++) {
        int row0 = wid * 64 + m * 16 + g * 4;
        #pragma unroll
        for (int nf = 0; nf < 2; nf++) {
            int col = bx + nf * 16 + (l & 15);
            #pragma unroll
            for (int r = 0; r < 4; r++) {
                float h1 = acc1[m][nf][r], h2 = acc2[m][nf][r];
                float sil = h2 / (1.0f + __expf(-h2));
                C[(size_t)(row0 + r) * DFF + col] = f2bf(h1 * sil);
            }
        }
    }
}

// ---------------- per-expert top-CAP via bitonic sort ----------------
__global__ __launch_bounds__(1024) void expert_select_kernel(const float* __restrict__ wfull,
                                                             float* __restrict__ sw,
                                                             int* __restrict__ sidx,
                                                             int* __restrict__ slot) {
    __shared__ unsigned long long keys[2048];
    int e = blockIdx.x;
    int t = threadIdx.x;
    for (int i = t; i < 2048; i += 1024) {
        float w = wfull[i * 8 + e];
        unsigned int wb = __float_as_uint(w);
        keys[i] = ((unsigned long long)wb << 32) | (unsigned long long)(0xFFFFFFFFu - (unsigned int)i);
    }
    __syncthreads();
    for (int k = 2; k <= 2048; k <<= 1) {
        for (int j = k >> 1; j > 0; j >>= 1) {
            for (int i = t; i < 2048; i += 1024) {
                int ixj = i ^ j;
                if (ixj > i) {
                    bool desc = ((i & k) == 0);
                    unsigned long long a = keys[i], b = keys[ixj];
                    if ((a < b) == desc) { keys[i] = b; keys[ixj] = a; }
                }
            }
            __syncthreads();
        }
    }
    if (t < CAP) {
        unsigned long long kk = keys[t];
        float w = __uint_as_float((unsigned int)(kk >> 32));
        int idx = (int)(0xFFFFFFFFu - (unsigned int)(kk & 0xFFFFFFFFu));
        sw[e * CAP + t] = w;
        sidx[e * CAP + t] = idx;
        if (w > 0.f) slot[idx * 8 + e] = t;
    }
}

// ---------------- gather tokens -> bf16 ----------------
__global__ __launch_bounds__(256) void gather_tok_kernel(const float* __restrict__ hn,
                                                         const int* __restrict__ sidx,
                                                         const float* __restrict__ sw,
                                                         unsigned short* __restrict__ tok) {
    int ec = blockIdx.x;
    int tid = threadIdx.x;
    float w = sw[ec];
    int src = sidx[ec];
    const float* s = hn + (size_t)src * DMODEL;
    unsigned short* d = tok + (size_t)ec * DMODEL;
    for (int i = tid; i < DMODEL; i += 256) d[i] = (w > 0.f) ? f2bf(s[i]) : 0;
}

// ---------------- final combine ----------------
__global__ __launch_bounds__(256) void combine_kernel(const float* __restrict__ h,
                                                      const float* __restrict__ out_e,
                                                      const int* __restrict__ slot,
                                                      const float* __restrict__ wfull,
                                                      const float* __restrict__ gate_sum,
                                                      float* __restrict__ out) {
    int t = blockIdx.x;
    int tid = threadIdx.x;
    for (int d = tid; d < DMODEL; d += 256) {
        float acc = h[(size_t)t * DMODEL + d];
        #pragma unroll
        for (int e = 0; e < 8; e++) {
            int c = slot[t * 8 + e];
            if (c >= 0) acc += wfull[t * 8 + e] * out_e[((size_t)(e * CAP + c)) * DMODEL + d];
        }
        out[(size_t)t * DMODEL + d] = acc;
    }
    if (t == 0 && tid == 0) {
        float a = 0.f;
        #pragma unroll
        for (int e = 0; e < 8; e++) { float m = gate_sum[e] / (float)T_TOK; a += m * m; }
        out[(size_t)T_TOK * DMODEL] = 8.0f * a;
    }
}

extern "C" void kernel_launch(void* const* d_in, const int* in_sizes, int n_in,
                              void* d_out, int out_size, void* d_ws, size_t ws_size,
                              hipStream_t stream) {
    const float* x     = (const float*)d_in[0];
    const int*   gtm   = (const int*)d_in[2];
    const float* Wq    = (const float*)d_in[3];
    const float* Wk    = (const float*)d_in[4];
    const float* Wv    = (const float*)d_in[5];
    const float* Wo    = (const float*)d_in[6];
    const float* g1    = (const float*)d_in[7];
    const float* g2    = (const float*)d_in[8];
    const float* Wgate = (const float*)d_in[9];
    const float* W1    = (const float*)d_in[10];
    const float* W2    = (const float*)d_in[11];
    float* out = (float*)d_out;

    char* ws = (char*)d_ws;
    unsigned short* Qh   = (unsigned short*)(ws + 0);
    unsigned short* Ql   = (unsigned short*)(ws + 4194304);
    unsigned short* Kh   = (unsigned short*)(ws + 8388608);
    unsigned short* Kl   = (unsigned short*)(ws + 12582912);
    unsigned short* Vtb  = (unsigned short*)(ws + 16777216);
    unsigned short* act  = (unsigned short*)(ws + 0);           // MoE phase; Q/K dead
    unsigned short* xn   = (unsigned short*)(ws + 20971520);
    unsigned short* attno= (unsigned short*)(ws + 25165824);
    float* hb    = (float*)(ws + 29360128);
    float* hnb   = (float*)(ws + 37748736);
    float* oute  = (float*)(ws + 46137344);
    unsigned short* tok = (unsigned short*)(ws + 54525952);
    float* ropec = (float*)(ws + 58720256);
    float* ropes = (float*)(ws + 58851328);
    float* wfull = (float*)(ws + 58982400);
    int*   slot  = (int*)(ws + 59047936);
    float* sw    = (float*)(ws + 59113472);
    int*   sidx  = (int*)(ws + 59121664);
    float* gsum  = (float*)(ws + 59129856);
    int*   gidx  = (int*)(ws + 59131904);
    int*   gcnt  = (int*)(ws + 59133952);
    unsigned short* Kgh = (unsigned short*)(ws + 59140096);     // 512 KB
    unsigned short* Kgl = (unsigned short*)(ws + 59664384);     // 512 KB
    unsigned short* Vgt = (unsigned short*)(ws + 60188672);     // 512 KB
    unsigned short* Qgh = (unsigned short*)(ws + 60712960);     // 512 KB
    unsigned short* Qgl = (unsigned short*)(ws + 61237248);     // 512 KB

    rope_table_kernel<<<S_LEN, 32, 0, stream>>>(ropec, ropes, gsum);
    gscan_kernel<<<2, 1024, 0, stream>>>(gtm, gidx, gcnt);
    rmsnorm_kernel<<<T_TOK, 256, 0, stream>>>(x, g1, xn);

    gemm_qkv_rope<<<dim3(48, 16, 1), 256, 0, stream>>>(
        xn, Wq, Wk, Wv, ropec, ropes, Qh, Ql, Kh, Kl, Vtb);

    gather_gkv_kernel<<<32, 256, 0, stream>>>(
        Qh, Ql, Kh, Kl, Vtb, gidx, gcnt, Qgh, Qgl, Kgh, Kgl, Vgt);

    attn_mfma_kernel<<<dim3(16, 16, 2), 256, 0, stream>>>(
        Qh, Ql, Kh, Kl, Vtb, Kgh, Kgl, Vgt, gtm, gcnt, attno);

    attn_gq_kernel<<<dim3(2, 16, 2), 256, 0, stream>>>(
        Qgh, Qgl, Kh, Kl, Vtb, gidx, gcnt, attno);

    // h = x + attno @ Wo  (f32 Wo read directly)
    gemm_bf32<1><<<dim3(32, 16, 1), 256, 0, stream>>>(
        attno, Wo, x, hb, 1024, 1024, 0, 0, 0);

    rmsnorm_gate_kernel<<<T_TOK, 256, 0, stream>>>(hb, g2, Wgate, hnb, wfull, slot, gsum);
    expert_select_kernel<<<NE, 1024, 0, stream>>>(wfull, sw, sidx, slot);
    gather_tok_kernel<<<NE * CAP, 256, 0, stream>>>(hnb, sidx, sw, tok);

    gemm_w1_fused<<<dim3(128, 8, 1), 256, 0, stream>>>(tok, W1, act);
    gemm_bf32<0><<<dim3(32, 2, 8), 256, 0, stream>>>(
        act, W2, nullptr, oute, 4096, 4096,
        (long long)CAP * DFF, (long long)DFF * 1024, (long long)CAP * 1024);

    combine_kernel<<<T_TOK, 256, 0, stream>>>(hb, oute, slot, wfull, gsum, out);
}

// Round 14
// 375.579 us; speedup vs baseline: 1.9545x; 1.4762x over previous
//
#include <hip/hip_runtime.h>
#include <hip/hip_bf16.h>
#include <math.h>

#define T_TOK 2048
#define DMODEL 1024
#define NH 16
#define HD 64
#define S_LEN 1024
#define NE 8
#define CAP 256
#define DFF 4096

typedef __attribute__((ext_vector_type(8))) short bf16x8;
typedef __attribute__((ext_vector_type(4))) float f32x4;

__device__ inline unsigned short f2bf(float f) {
    union { float f; unsigned int u; } x; x.f = f;
    unsigned int u = x.u;
    unsigned int r = (u + 0x7FFFu + ((u >> 16) & 1u)) >> 16;
    return (unsigned short)r;
}

__device__ inline float bf2f(unsigned short h) {
    union { unsigned int u; float f; } x; x.u = (unsigned int)h << 16; return x.f;
}

// packed f32x2 -> bf16x2 (RTNE); lo in low 16 bits
__device__ inline unsigned int pkbf(float lo, float hi) {
    __hip_bfloat162 h2 = __float22bfloat162_rn(make_float2(lo, hi));
    unsigned int r;
    __builtin_memcpy(&r, &h2, 4);
    return r;
}

__device__ inline void gload16(const void* g, void* l) {
    __builtin_amdgcn_global_load_lds(
        (const __attribute__((address_space(1))) unsigned int*)g,
        (__attribute__((address_space(3))) unsigned int*)l, 16, 0, 0);
}

// ---------------- RoPE table (+ gsum zero) ----------------
__global__ void rope_table_kernel(float* __restrict__ rc, float* __restrict__ rs,
                                  float* __restrict__ gsum) {
    int s = blockIdx.x;
    int i = threadIdx.x;
    float invf = powf(10000.0f, -(float)(2 * i) / 64.0f);
    float ang = (float)s * invf;
    rc[s * 32 + i] = cosf(ang);
    rs[s * 32 + i] = sinf(ang);
    if (blockIdx.x == 0 && threadIdx.x < 8) gsum[threadIdx.x] = 0.f;
}

// ---------------- global-token scan: packed indices + count per batch ----------------
__global__ __launch_bounds__(1024) void gscan_kernel(const int* __restrict__ gtm,
                                                     int* __restrict__ gidx,
                                                     int* __restrict__ gcnt) {
    __shared__ int ps[1024];
    int b = blockIdx.x, t = threadIdx.x;
    int f = gtm[b * 1024 + t] ? 1 : 0;
    ps[t] = f;
    __syncthreads();
    for (int off = 1; off < 1024; off <<= 1) {
        int v = (t >= off) ? ps[t - off] : 0;
        __syncthreads();
        ps[t] += v;
        __syncthreads();
    }
    if (f) {
        int pos = ps[t] - 1;
        if (pos < 128) gidx[b * 128 + pos] = t;
    }
    if (t == 1023) gcnt[b] = ps[1023] > 128 ? 128 : ps[1023];
}

// ---------------- RMSNorm (OUTBF: 1 -> bf16 out, 0 -> f32 out) ----------------
template <int OUTBF>
__global__ __launch_bounds__(256) void rmsnorm_kernel(const float* __restrict__ x,
                                                      const float* __restrict__ g,
                                                      void* __restrict__ yv) {
    __shared__ float red[256];
    int t = blockIdx.x;
    int tid = threadIdx.x;
    const float* xr = x + (size_t)t * DMODEL;
    float ss = 0.f;
    for (int d = tid; d < DMODEL; d += 256) { float v = xr[d]; ss += v * v; }
    red[tid] = ss; __syncthreads();
    for (int o = 128; o > 0; o >>= 1) { if (tid < o) red[tid] += red[tid + o]; __syncthreads(); }
    float scale = 1.0f / sqrtf(red[0] / (float)DMODEL + 1e-6f);
    if (OUTBF) {
        unsigned short* yr = (unsigned short*)yv + (size_t)t * DMODEL;
        for (int d = tid; d < DMODEL; d += 256) yr[d] = f2bf(g[d] * xr[d] * scale);
    } else {
        float* yr = (float*)yv + (size_t)t * DMODEL;
        for (int d = tid; d < DMODEL; d += 256) yr[d] = g[d] * xr[d] * scale;
    }
}

// ---------------- gate: one wave per token, register-only; writes wfull + slot=-1 ----------------
__global__ __launch_bounds__(256) void gate_kernel(const float* __restrict__ hn,
                                                   const float* __restrict__ Wgate,
                                                   float* __restrict__ wfull,
                                                   int* __restrict__ slot,
                                                   float* __restrict__ gate_sum) {
    int tid = threadIdx.x;
    int w = tid >> 6, l = tid & 63;
    int t = blockIdx.x * 4 + w;
    int e = l & 7, g = l >> 3;
    const float* xr = hn + (size_t)t * DMODEL;
    const float* wp = Wgate + l;
    float acc = 0.f;
    #pragma unroll 8
    for (int kk = 0; kk < 128; kk++)
        acc += xr[g + 8 * kk] * wp[64 * kk];
    #pragma unroll
    for (int o = 8; o < 64; o <<= 1) acc += __shfl_xor(acc, o, 64);
    float m = acc;
    #pragma unroll
    for (int o = 1; o < 8; o <<= 1) m = fmaxf(m, __shfl_xor(m, o, 64));
    float p = __expf(acc - m);
    float s = p;
    #pragma unroll
    for (int o = 1; o < 8; o <<= 1) s += __shfl_xor(s, o, 64);
    float pr = p / s;
    unsigned long long key = ((unsigned long long)__float_as_uint(pr) << 32) | (unsigned)(7 - e);
    unsigned long long k1 = key;
    #pragma unroll
    for (int o = 1; o < 8; o <<= 1) { unsigned long long t2 = __shfl_xor(k1, o, 64); if (t2 > k1) k1 = t2; }
    int e1 = 7 - (int)(k1 & 7);
    unsigned long long key2 = (e == e1) ? 0ull : key;
    unsigned long long k2 = key2;
    #pragma unroll
    for (int o = 1; o < 8; o <<= 1) { unsigned long long t2 = __shfl_xor(k2, o, 64); if (t2 > k2) k2 = t2; }
    int e2 = 7 - (int)(k2 & 7);
    if (l < 8) {
        wfull[t * 8 + e] = (e == e1 || e == e2) ? pr : 0.f;
        slot[t * 8 + e] = -1;
        atomicAdd(&gate_sum[e], pr);
    }
}

// ---------------- fused QKV GEMM + RoPE + hi/lo + V-transpose (B reg-prefetch) ----------------
__global__ __launch_bounds__(256) void gemm_qkv_rope(const unsigned short* __restrict__ xn,
                                                     const float* __restrict__ Wq,
                                                     const float* __restrict__ Wk,
                                                     const float* __restrict__ Wv,
                                                     const float* __restrict__ rc,
                                                     const float* __restrict__ rs,
                                                     unsigned short* __restrict__ Qh,
                                                     unsigned short* __restrict__ Ql,
                                                     unsigned short* __restrict__ Kh,
                                                     unsigned short* __restrict__ Kl,
                                                     unsigned short* __restrict__ Vtb) {
    __shared__ unsigned short As[128 * 64];
    __shared__ unsigned int Bp[64 * 32];
    const int mat = blockIdx.x >> 4;
    const int h = blockIdx.x & 15;
    const float* B = ((mat == 0) ? Wq : (mat == 1) ? Wk : Wv) + h * 64;
    const int by = blockIdx.y * 128;
    const int tid = threadIdx.x, l = tid & 63, wid = tid >> 6;
    const int g = l >> 4;
    const int kp = tid >> 3;
    const int nc = tid & 7;
    const int chunk = kp >> 2, within = kp & 3;

    f32x4 acc[2][4] = {};

    const float* Brow = B + (size_t)(2 * kp) * 1024 + nc * 8;
    float4 a0 = *(const float4*)(Brow);
    float4 a1 = *(const float4*)(Brow + 4);
    float4 b0 = *(const float4*)(Brow + 1024);
    float4 b1 = *(const float4*)(Brow + 1028);

    for (int k0 = 0; k0 < 1024; k0 += 64) {
        #pragma unroll
        for (int i = 0; i < 4; i++) {
            int c = i * 256 + tid;
            int row = c >> 3, sl = c & 7, gs = sl ^ (row & 7);
            gload16(xn + (size_t)(by + row) * 1024 + k0 + gs * 8, &As[c * 8]);
        }
        unsigned int p[8];
        p[0] = pkbf(a0.x, b0.x); p[1] = pkbf(a0.y, b0.y);
        p[2] = pkbf(a0.z, b0.z); p[3] = pkbf(a0.w, b0.w);
        p[4] = pkbf(a1.x, b1.x); p[5] = pkbf(a1.y, b1.y);
        p[6] = pkbf(a1.z, b1.z); p[7] = pkbf(a1.w, b1.w);
        #pragma unroll
        for (int i = 0; i < 8; i++) {
            int n_loc = nc * 8 + i;
            int idx = n_loc * 32 + ((chunk ^ (n_loc & 7)) << 2) + within;
            Bp[idx] = p[i];
        }
        __syncthreads();
        if (k0 + 64 < 1024) {
            const float* Bn = B + (size_t)(k0 + 64 + 2 * kp) * 1024 + nc * 8;
            a0 = *(const float4*)(Bn);
            a1 = *(const float4*)(Bn + 4);
            b0 = *(const float4*)(Bn + 1024);
            b1 = *(const float4*)(Bn + 1028);
        }
        #pragma unroll
        for (int ks = 0; ks < 2; ks++) {
            bf16x8 af[2];
            #pragma unroll
            for (int m = 0; m < 2; m++) {
                int row = wid * 32 + m * 16 + (l & 15);
                int sl = (ks * 4 + g) ^ (row & 7);
                af[m] = *(const bf16x8*)&As[row * 64 + sl * 8];
            }
            #pragma unroll
            for (int nf = 0; nf < 4; nf++) {
                int n_loc = nf * 16 + (l & 15);
                int base = n_loc * 32 + (((ks * 4 + g) ^ (n_loc & 7)) << 2);
                bf16x8 bfr = *(const bf16x8*)&Bp[base];
                #pragma unroll
                for (int m = 0; m < 2; m++)
                    acc[m][nf] = __builtin_amdgcn_mfma_f32_16x16x32_bf16(af[m], bfr, acc[m][nf], 0, 0, 0);
            }
        }
        __syncthreads();
    }

    if (mat < 2) {
        unsigned short* Dh = (mat == 0) ? Qh : Kh;
        unsigned short* Dl = (mat == 0) ? Ql : Kl;
        float scale = (mat == 0) ? 0.125f : 1.0f;
        #pragma unroll
        for (int m = 0; m < 2; m++)
            #pragma unroll
            for (int r = 0; r < 4; r++) {
                int t = by + wid * 32 + m * 16 + g * 4 + r;
                int b = t >> 10, s = t & 1023;
                size_t ob = ((size_t)(b * 16 + h) * 1024 + s) * 64;
                #pragma unroll
                for (int pr = 0; pr < 2; pr++) {
                    int i = pr * 16 + (l & 15);
                    float c = rc[s * 32 + i], sn = rs[s * 32 + i];
                    float a = acc[m][pr][r], bb = acc[m][pr + 2][r];
                    float v0 = (a * c - bb * sn) * scale;
                    float v1 = (bb * c + a * sn) * scale;
                    unsigned short h0 = f2bf(v0), h1 = f2bf(v1);
                    Dh[ob + i] = h0;      Dl[ob + i] = f2bf(v0 - bf2f(h0));
                    Dh[ob + i + 32] = h1; Dl[ob + i + 32] = f2bf(v1 - bf2f(h1));
                }
            }
    } else {
        #pragma unroll
        for (int m = 0; m < 2; m++) {
            int t0 = by + wid * 32 + m * 16 + g * 4;
            int b = t0 >> 10, s0 = t0 & 1023;
            #pragma unroll
            for (int nf = 0; nf < 4; nf++) {
                int d = nf * 16 + (l & 15);
                unsigned short tmp[4];
                #pragma unroll
                for (int r = 0; r < 4; r++) tmp[r] = f2bf(acc[m][nf][r]);
                *(uint2*)&Vtb[((size_t)(b * 16 + h) * 64 + d) * 1024 + s0] = *(uint2*)tmp;
            }
        }
    }
}

// ---------------- gather global-token Q/K/V into packed tiles ----------------
__global__ __launch_bounds__(256) void gather_gkv_kernel(const unsigned short* __restrict__ Qh,
                                                         const unsigned short* __restrict__ Ql,
                                                         const unsigned short* __restrict__ Kh,
                                                         const unsigned short* __restrict__ Kl,
                                                         const unsigned short* __restrict__ Vtb,
                                                         const int* __restrict__ gidx,
                                                         const int* __restrict__ gcnt,
                                                         unsigned short* __restrict__ Qgh,
                                                         unsigned short* __restrict__ Qgl,
                                                         unsigned short* __restrict__ Kgh,
                                                         unsigned short* __restrict__ Kgl,
                                                         unsigned short* __restrict__ Vgt) {
    int bh = blockIdx.x;
    int b = bh >> 4;
    int cnt = gcnt[b];
    int tid = threadIdx.x;
    for (int i = tid; i < 128 * 8; i += 256) {
        int slot = i >> 3, c8 = (i & 7) * 8;
        size_t dst = ((size_t)bh * 128 + slot) * 64 + c8;
        if (slot < cnt) {
            int idx = gidx[b * 128 + slot];
            size_t src = ((size_t)bh * 1024 + idx) * 64 + c8;
            *(uint4*)(Qgh + dst) = *(const uint4*)(Qh + src);
            *(uint4*)(Qgl + dst) = *(const uint4*)(Ql + src);
            *(uint4*)(Kgh + dst) = *(const uint4*)(Kh + src);
            *(uint4*)(Kgl + dst) = *(const uint4*)(Kl + src);
        } else {
            uint4 z = {0, 0, 0, 0};
            *(uint4*)(Qgh + dst) = z;
            *(uint4*)(Qgl + dst) = z;
            *(uint4*)(Kgh + dst) = z;
            *(uint4*)(Kgl + dst) = z;
        }
    }
    for (int i = tid; i < 64 * 16; i += 256) {
        int d = i >> 4, s8 = (i & 15) * 8;
        unsigned short tmp[8];
        #pragma unroll
        for (int u = 0; u < 8; u++) {
            int slot = s8 + u;
            tmp[u] = (slot < cnt) ? Vtb[((size_t)bh * 64 + d) * 1024 + gidx[b * 128 + slot]]
                                  : (unsigned short)0;
        }
        *(uint4*)(Vgt + ((size_t)bh * 64 + d) * 128 + s8) = *(uint4*)tmp;
    }
}

// ---------------- sparse flash attention: window tiles + gathered global tiles ----------------
__global__ __launch_bounds__(256) void attn_mfma_kernel(const unsigned short* __restrict__ Qh,
                                                        const unsigned short* __restrict__ Ql,
                                                        const unsigned short* __restrict__ Kh,
                                                        const unsigned short* __restrict__ Kl,
                                                        const unsigned short* __restrict__ Vtb,
                                                        const unsigned short* __restrict__ Kgh,
                                                        const unsigned short* __restrict__ Kgl,
                                                        const unsigned short* __restrict__ Vgt,
                                                        const int* __restrict__ gtm,
                                                        const int* __restrict__ gcnt,
                                                        unsigned short* __restrict__ o) {
    __shared__ unsigned short Ksh[2][64 * 64];
    __shared__ unsigned short Ksl[2][64 * 64];
    __shared__ unsigned short Vs[2][64 * 64];
    __shared__ unsigned short Pl[4][16 * 64];
    const int qt = blockIdx.x, h = blockIdx.y, b = blockIdx.z;
    const int bh = b * 16 + h;
    const int tid = threadIdx.x, l = tid & 63, w = tid >> 6;
    const int q0 = qt * 64 + w * 16;
    const int jt_lo = (qt >= 4) ? (qt - 4) : 0;
    const int nwin = qt - jt_lo + 1;
    const int ntiles = nwin + 2;
    const int cnt = gcnt[b];
    const unsigned short* Qhb = Qh + (size_t)bh * 1024 * 64;
    const unsigned short* Qlb = Ql + (size_t)bh * 1024 * 64;
    const unsigned short* Khb = Kh + (size_t)bh * 1024 * 64;
    const unsigned short* Klb = Kl + (size_t)bh * 1024 * 64;
    const unsigned short* Vbh = Vtb + (size_t)bh * 64 * 1024;
    const unsigned short* Kghb = Kgh + (size_t)bh * 128 * 64;
    const unsigned short* Kglb = Kgl + (size_t)bh * 128 * 64;
    const unsigned short* Vgtb = Vgt + (size_t)bh * 64 * 128;
    const int* gb = gtm + b * 1024;

    bf16x8 afh[2], afl[2];
    #pragma unroll
    for (int ks = 0; ks < 2; ks++) {
        size_t off = (size_t)(q0 + (l & 15)) * 64 + ks * 32 + (l >> 4) * 8;
        afh[ks] = *(const bf16x8*)(Qhb + off);
        afl[ks] = *(const bf16x8*)(Qlb + off);
    }

    f32x4 acc_o[4] = {};
    float m_run[4], l_run[4];
    #pragma unroll
    for (int r = 0; r < 4; r++) { m_run[r] = -1e30f; l_run[r] = 0.f; }

    auto STAGE = [&](int ti, int buf) {
        if (ti < nwin) {
            int j0s = (jt_lo + ti) * 64;
            #pragma unroll
            for (int i = 0; i < 2; i++) {
                int c = i * 256 + tid, row = c >> 3, sl = c & 7, gs = sl ^ (row & 7);
                gload16(Khb + (size_t)(j0s + row) * 64 + gs * 8, &Ksh[buf][c * 8]);
                gload16(Klb + (size_t)(j0s + row) * 64 + gs * 8, &Ksl[buf][c * 8]);
                gload16(Vbh + (size_t)row * 1024 + j0s + gs * 8, &Vs[buf][c * 8]);
            }
        } else {
            int g0 = (ti - nwin) * 64;
            #pragma unroll
            for (int i = 0; i < 2; i++) {
                int c = i * 256 + tid, row = c >> 3, sl = c & 7, gs = sl ^ (row & 7);
                gload16(Kghb + (size_t)(g0 + row) * 64 + gs * 8, &Ksh[buf][c * 8]);
                gload16(Kglb + (size_t)(g0 + row) * 64 + gs * 8, &Ksl[buf][c * 8]);
                gload16(Vgtb + (size_t)row * 128 + g0 + gs * 8, &Vs[buf][c * 8]);
            }
        }
    };

    STAGE(0, 0);
    int cur = 0;

    for (int ti = 0; ti < ntiles; ti++) {
        __syncthreads();
        if (ti + 1 < ntiles) STAGE(ti + 1, cur ^ 1);

        f32x4 sv[4] = {};
        __builtin_amdgcn_s_setprio(1);
        #pragma unroll
        for (int n = 0; n < 4; n++) {
            #pragma unroll
            for (int ks = 0; ks < 2; ks++) {
                int row = n * 16 + (l & 15);
                int sl = (ks * 4 + (l >> 4)) ^ (row & 7);
                bf16x8 khf = *(const bf16x8*)&Ksh[cur][row * 64 + sl * 8];
                bf16x8 klf = *(const bf16x8*)&Ksl[cur][row * 64 + sl * 8];
                sv[n] = __builtin_amdgcn_mfma_f32_16x16x32_bf16(afl[ks], khf, sv[n], 0, 0, 0);
                sv[n] = __builtin_amdgcn_mfma_f32_16x16x32_bf16(afh[ks], klf, sv[n], 0, 0, 0);
                sv[n] = __builtin_amdgcn_mfma_f32_16x16x32_bf16(afh[ks], khf, sv[n], 0, 0, 0);
            }
        }
        __builtin_amdgcn_s_setprio(0);

        if (ti < nwin) {
            int j0 = (jt_lo + ti) * 64;
            int gk[4];
            #pragma unroll
            for (int n = 0; n < 4; n++) gk[n] = gb[j0 + n * 16 + (l & 15)];
            #pragma unroll
            for (int n = 0; n < 4; n++)
                #pragma unroll
                for (int r = 0; r < 4; r++) {
                    int q = q0 + (l >> 4) * 4 + r;
                    int k = j0 + n * 16 + (l & 15);
                    bool allowed = (k <= q) && (q - k < 256) && !gk[n];
                    if (!allowed) sv[n][r] = -1e30f;
                }
        } else {
            int s0 = (ti - nwin) * 64;
            #pragma unroll
            for (int n = 0; n < 4; n++) {
                int slot = s0 + n * 16 + (l & 15);
                bool allowed = slot < cnt;
                #pragma unroll
                for (int r = 0; r < 4; r++)
                    if (!allowed) sv[n][r] = -1e30f;
            }
        }

        {
            float tm[4], corr[4], rsum[4];
            #pragma unroll
            for (int r = 0; r < 4; r++)
                tm[r] = fmaxf(fmaxf(sv[0][r], sv[1][r]), fmaxf(sv[2][r], sv[3][r]));
            #pragma unroll
            for (int wd = 1; wd <= 8; wd <<= 1)
                #pragma unroll
                for (int r = 0; r < 4; r++) tm[r] = fmaxf(tm[r], __shfl_xor(tm[r], wd, 64));
            #pragma unroll
            for (int r = 0; r < 4; r++) {
                float mn = fmaxf(m_run[r], tm[r]);
                corr[r] = __expf(m_run[r] - mn);
                m_run[r] = mn;
                rsum[r] = 0.f;
            }
            #pragma unroll
            for (int n = 0; n < 4; n++)
                #pragma unroll
                for (int r = 0; r < 4; r++) {
                    float p = __expf(sv[n][r] - m_run[r]);
                    sv[n][r] = p;
                    rsum[r] += p;
                }
            #pragma unroll
            for (int wd = 1; wd <= 8; wd <<= 1)
                #pragma unroll
                for (int r = 0; r < 4; r++) rsum[r] += __shfl_xor(rsum[r], wd, 64);
            #pragma unroll
            for (int r = 0; r < 4; r++) l_run[r] = l_run[r] * corr[r] + rsum[r];
            #pragma unroll
            for (int nd = 0; nd < 4; nd++)
                #pragma unroll
                for (int r = 0; r < 4; r++) acc_o[nd][r] *= corr[r];
            #pragma unroll
            for (int n = 0; n < 4; n++)
                #pragma unroll
                for (int r = 0; r < 4; r++) {
                    int qr = (l >> 4) * 4 + r;
                    int kc = n * 16 + (l & 15);
                    int byte = (qr * 128 + kc * 2) ^ ((qr & 7) << 4);
                    Pl[w][byte >> 1] = f2bf(sv[n][r]);
                }
        }

        asm volatile("s_waitcnt lgkmcnt(0)" ::: "memory");
        __builtin_amdgcn_sched_barrier(0);

        __builtin_amdgcn_s_setprio(1);
        #pragma unroll
        for (int ks = 0; ks < 2; ks++) {
            int prow = l & 15;
            int psl = (ks * 4 + (l >> 4)) ^ (prow & 7);
            bf16x8 pa = *(const bf16x8*)&Pl[w][prow * 64 + psl * 8];
            #pragma unroll
            for (int nd = 0; nd < 4; nd++) {
                int row = nd * 16 + (l & 15);
                int sl = (ks * 4 + (l >> 4)) ^ (row & 7);
                bf16x8 vf = *(const bf16x8*)&Vs[cur][row * 64 + sl * 8];
                acc_o[nd] = __builtin_amdgcn_mfma_f32_16x16x32_bf16(pa, vf, acc_o[nd], 0, 0, 0);
            }
        }
        __builtin_amdgcn_s_setprio(0);
        cur ^= 1;
    }

    #pragma unroll
    for (int r = 0; r < 4; r++) {
        float inv = 1.0f / l_run[r];
        int t_ = b * 1024 + q0 + (l >> 4) * 4 + r;
        #pragma unroll
        for (int nd = 0; nd < 4; nd++) {
            int col = h * 64 + nd * 16 + (l & 15);
            o[(size_t)t_ * 1024 + col] = f2bf(acc_o[nd][r] * inv);
        }
    }
}

// ---------------- dense flash attention for gathered global-q rows (MFMA) ----------------
__global__ __launch_bounds__(256) void attn_gq_kernel(const unsigned short* __restrict__ Qgh,
                                                      const unsigned short* __restrict__ Qgl,
                                                      const unsigned short* __restrict__ Kh,
                                                      const unsigned short* __restrict__ Kl,
                                                      const unsigned short* __restrict__ Vtb,
                                                      const int* __restrict__ gidx,
                                                      const int* __restrict__ gcnt,
                                                      unsigned short* __restrict__ o) {
    __shared__ unsigned short Ksh[2][64 * 64];
    __shared__ unsigned short Ksl[2][64 * 64];
    __shared__ unsigned short Vs[2][64 * 64];
    __shared__ unsigned short Pl[4][16 * 64];
    const int qt = blockIdx.x, h = blockIdx.y, b = blockIdx.z;
    const int bh = b * 16 + h;
    const int cnt = gcnt[b];
    if (qt * 64 >= cnt) return;
    const int tid = threadIdx.x, l = tid & 63, w = tid >> 6;
    const int q0 = qt * 64 + w * 16;   // slot base
    const unsigned short* Qhb = Qgh + (size_t)bh * 128 * 64;
    const unsigned short* Qlb = Qgl + (size_t)bh * 128 * 64;
    const unsigned short* Khb = Kh + (size_t)bh * 1024 * 64;
    const unsigned short* Klb = Kl + (size_t)bh * 1024 * 64;
    const unsigned short* Vbh = Vtb + (size_t)bh * 64 * 1024;

    bf16x8 afh[2], afl[2];
    #pragma unroll
    for (int ks = 0; ks < 2; ks++) {
        size_t off = (size_t)(q0 + (l & 15)) * 64 + ks * 32 + (l >> 4) * 8;
        afh[ks] = *(const bf16x8*)(Qhb + off);
        afl[ks] = *(const bf16x8*)(Qlb + off);
    }

    f32x4 acc_o[4] = {};
    float m_run[4], l_run[4];
    #pragma unroll
    for (int r = 0; r < 4; r++) { m_run[r] = -1e30f; l_run[r] = 0.f; }

    #pragma unroll
    for (int i = 0; i < 2; i++) {
        int c = i * 256 + tid, row = c >> 3, sl = c & 7, gs = sl ^ (row & 7);
        gload16(Khb + (size_t)row * 64 + gs * 8, &Ksh[0][c * 8]);
        gload16(Klb + (size_t)row * 64 + gs * 8, &Ksl[0][c * 8]);
        gload16(Vbh + (size_t)row * 1024 + gs * 8, &Vs[0][c * 8]);
    }
    int cur = 0;

    for (int jt = 0; jt < 16; jt++) {
        __syncthreads();
        if (jt < 15) {
            int jn = (jt + 1) * 64, nb = cur ^ 1;
            #pragma unroll
            for (int i = 0; i < 2; i++) {
                int c = i * 256 + tid, row = c >> 3, sl = c & 7, gs = sl ^ (row & 7);
                gload16(Khb + (size_t)(jn + row) * 64 + gs * 8, &Ksh[nb][c * 8]);
                gload16(Klb + (size_t)(jn + row) * 64 + gs * 8, &Ksl[nb][c * 8]);
                gload16(Vbh + (size_t)row * 1024 + jn + gs * 8, &Vs[nb][c * 8]);
            }
        }

        f32x4 sv[4] = {};
        __builtin_amdgcn_s_setprio(1);
        #pragma unroll
        for (int n = 0; n < 4; n++) {
            #pragma unroll
            for (int ks = 0; ks < 2; ks++) {
                int row = n * 16 + (l & 15);
                int sl = (ks * 4 + (l >> 4)) ^ (row & 7);
                bf16x8 khf = *(const bf16x8*)&Ksh[cur][row * 64 + sl * 8];
                bf16x8 klf = *(const bf16x8*)&Ksl[cur][row * 64 + sl * 8];
                sv[n] = __builtin_amdgcn_mfma_f32_16x16x32_bf16(afl[ks], khf, sv[n], 0, 0, 0);
                sv[n] = __builtin_amdgcn_mfma_f32_16x16x32_bf16(afh[ks], klf, sv[n], 0, 0, 0);
                sv[n] = __builtin_amdgcn_mfma_f32_16x16x32_bf16(afh[ks], khf, sv[n], 0, 0, 0);
            }
        }
        __builtin_amdgcn_s_setprio(0);

        // no masking: global-q rows attend to every column
        {
            float tm[4], corr[4], rsum[4];
            #pragma unroll
            for (int r = 0; r < 4; r++)
                tm[r] = fmaxf(fmaxf(sv[0][r], sv[1][r]), fmaxf(sv[2][r], sv[3][r]));
            #pragma unroll
            for (int wd = 1; wd <= 8; wd <<= 1)
                #pragma unroll
                for (int r = 0; r < 4; r++) tm[r] = fmaxf(tm[r], __shfl_xor(tm[r], wd, 64));
            #pragma unroll
            for (int r = 0; r < 4; r++) {
                float mn = fmaxf(m_run[r], tm[r]);
                corr[r] = __expf(m_run[r] - mn);
                m_run[r] = mn;
                rsum[r] = 0.f;
            }
            #pragma unroll
            for (int n = 0; n < 4; n++)
                #pragma unroll
                for (int r = 0; r < 4; r++) {
                    float p = __expf(sv[n][r] - m_run[r]);
                    sv[n][r] = p;
                    rsum[r] += p;
                }
            #pragma unroll
            for (int wd = 1; wd <= 8; wd <<= 1)
                #pragma unroll
                for (int r = 0; r < 4; r++) rsum[r] += __shfl_xor(rsum[r], wd, 64);
            #pragma unroll
            for (int r = 0; r < 4; r++) l_run[r] = l_run[r] * corr[r] + rsum[r];
            #pragma unroll
            for (int nd = 0; nd < 4; nd++)
                #pragma unroll
                for (int r = 0; r < 4; r++) acc_o[nd][r] *= corr[r];
            #pragma unroll
            for (int n = 0; n < 4; n++)
                #pragma unroll
                for (int r = 0; r < 4; r++) {
                    int qr = (l >> 4) * 4 + r;
                    int kc = n * 16 + (l & 15);
                    int byte = (qr * 128 + kc * 2) ^ ((qr & 7) << 4);
                    Pl[w][byte >> 1] = f2bf(sv[n][r]);
                }
        }

        asm volatile("s_waitcnt lgkmcnt(0)" ::: "memory");
        __builtin_amdgcn_sched_barrier(0);

        __builtin_amdgcn_s_setprio(1);
        #pragma unroll
        for (int ks = 0; ks < 2; ks++) {
            int prow = l & 15;
            int psl = (ks * 4 + (l >> 4)) ^ (prow & 7);
            bf16x8 pa = *(const bf16x8*)&Pl[w][prow * 64 + psl * 8];
            #pragma unroll
            for (int nd = 0; nd < 4; nd++) {
                int row = nd * 16 + (l & 15);
                int sl = (ks * 4 + (l >> 4)) ^ (row & 7);
                bf16x8 vf = *(const bf16x8*)&Vs[cur][row * 64 + sl * 8];
                acc_o[nd] = __builtin_amdgcn_mfma_f32_16x16x32_bf16(pa, vf, acc_o[nd], 0, 0, 0);
            }
        }
        __builtin_amdgcn_s_setprio(0);
        cur ^= 1;
    }

    #pragma unroll
    for (int r = 0; r < 4; r++) {
        int slot_r = q0 + (l >> 4) * 4 + r;
        if (slot_r < cnt) {
            int t_ = b * 1024 + gidx[b * 128 + slot_r];
            float inv = 1.0f / l_run[r];
            #pragma unroll
            for (int nd = 0; nd < 4; nd++) {
                int col = h * 64 + nd * 16 + (l & 15);
                o[(size_t)t_ * 1024 + col] = f2bf(acc_o[nd][r] * inv);
            }
        }
    }
}

// ---------------- generic fused GEMM: C(f32) = A(bf16) @ B(f32), B reg-prefetch ----------------
template <int RES>
__global__ __launch_bounds__(256) void gemm_bf32(const unsigned short* __restrict__ A,
                                                 const float* __restrict__ B,
                                                 const float* __restrict__ Rr,
                                                 float* __restrict__ C,
                                                 int K, int lda,
                                                 long long sA, long long sB, long long sC) {
    __shared__ unsigned short As[128 * 64];
    __shared__ unsigned int Bp[32 * 32];
    A += (long long)blockIdx.z * sA + (long long)blockIdx.y * 128 * lda;
    B += (long long)blockIdx.z * sB;
    C += (long long)blockIdx.z * sC + (long long)blockIdx.y * 128 * 1024;
    const float* Rp = RES ? (Rr + (long long)blockIdx.y * 128 * 1024) : nullptr;
    const int bx = blockIdx.x * 32;
    const int tid = threadIdx.x, l = tid & 63, wid = tid >> 6;
    const int g = l >> 4;
    const int kp = tid >> 3;
    const int nc = tid & 7;
    const int chunk = kp >> 2, within = kp & 3;

    f32x4 acc[2][2] = {};

    const float* Brow = B + (size_t)(2 * kp) * 1024 + bx + nc * 4;
    float4 a0 = *(const float4*)(Brow);
    float4 a1 = *(const float4*)(Brow + 1024);

    for (int k0 = 0; k0 < K; k0 += 64) {
        #pragma unroll
        for (int i = 0; i < 4; i++) {
            int c = i * 256 + tid;
            int row = c >> 3, sl = c & 7, gs = sl ^ (row & 7);
            gload16(A + (size_t)row * lda + k0 + gs * 8, &As[c * 8]);
        }
        unsigned int p1[4];
        p1[0] = pkbf(a0.x, a1.x); p1[1] = pkbf(a0.y, a1.y);
        p1[2] = pkbf(a0.z, a1.z); p1[3] = pkbf(a0.w, a1.w);
        #pragma unroll
        for (int i = 0; i < 4; i++) {
            int n_loc = nc * 4 + i;
            int idx = n_loc * 32 + ((chunk ^ (n_loc & 7)) << 2) + within;
            Bp[idx] = p1[i];
        }
        __syncthreads();
        if (k0 + 64 < K) {
            const float* Bn = B + (size_t)(k0 + 64 + 2 * kp) * 1024 + bx + nc * 4;
            a0 = *(const float4*)(Bn);
            a1 = *(const float4*)(Bn + 1024);
        }
        #pragma unroll
        for (int ks = 0; ks < 2; ks++) {
            bf16x8 af[2];
            #pragma unroll
            for (int m = 0; m < 2; m++) {
                int row = wid * 32 + m * 16 + (l & 15);
                int sl = (ks * 4 + g) ^ (row & 7);
                af[m] = *(const bf16x8*)&As[row * 64 + sl * 8];
            }
            #pragma unroll
            for (int nf = 0; nf < 2; nf++) {
                int n_loc = nf * 16 + (l & 15);
                int base = n_loc * 32 + (((ks * 4 + g) ^ (n_loc & 7)) << 2);
                bf16x8 bfr = *(const bf16x8*)&Bp[base];
                #pragma unroll
                for (int m = 0; m < 2; m++)
                    acc[m][nf] = __builtin_amdgcn_mfma_f32_16x16x32_bf16(af[m], bfr, acc[m][nf], 0, 0, 0);
            }
        }
        __syncthreads();
    }
    #pragma unroll
    for (int m = 0; m < 2; m++) {
        int row0 = wid * 32 + m * 16 + g * 4;
        #pragma unroll
        for (int nf = 0; nf < 2; nf++) {
            int col = bx + nf * 16 + (l & 15);
            #pragma unroll
            for (int r = 0; r < 4; r++) {
                size_t idx = (size_t)(row0 + r) * 1024 + col;
                float v = acc[m][nf][r];
                if (RES) v += Rp[idx];
                C[idx] = v;
            }
        }
    }
}

// ---------------- fused MoE W1 GEMM + SwiGLU (B reg-prefetch) ----------------
__global__ __launch_bounds__(256) void gemm_w1_fused(const unsigned short* __restrict__ tok,
                                                     const float* __restrict__ W1,
                                                     unsigned short* __restrict__ act) {
    __shared__ unsigned short As[256 * 64];
    __shared__ unsigned int B1p[32 * 32];
    __shared__ unsigned int B2p[32 * 32];
    const int e = blockIdx.y;
    const int bx = blockIdx.x * 32;
    const unsigned short* A = tok + (size_t)e * CAP * DMODEL;
    const float* B = W1 + (size_t)e * DMODEL * (2 * DFF);
    unsigned short* C = act + (size_t)e * CAP * DFF;
    const int tid = threadIdx.x, l = tid & 63, wid = tid >> 6;
    const int g = l >> 4;
    const int kp = tid >> 3;
    const int nc = tid & 7;
    const int chunk = kp >> 2, within = kp & 3;

    f32x4 acc1[4][2] = {};
    f32x4 acc2[4][2] = {};

    const float* Brow = B + (size_t)(2 * kp) * 8192 + bx + nc * 4;
    float4 a0 = *(const float4*)(Brow);
    float4 a1 = *(const float4*)(Brow + 8192);
    float4 c0 = *(const float4*)(Brow + 4096);
    float4 c1 = *(const float4*)(Brow + 4096 + 8192);

    for (int k0 = 0; k0 < DMODEL; k0 += 64) {
        #pragma unroll
        for (int i = 0; i < 8; i++) {
            int c = i * 256 + tid;
            int row = c >> 3, sl = c & 7, gs = sl ^ (row & 7);
            gload16(A + (size_t)row * DMODEL + k0 + gs * 8, &As[c * 8]);
        }
        unsigned int p1[4], p2[4];
        p1[0] = pkbf(a0.x, a1.x); p1[1] = pkbf(a0.y, a1.y);
        p1[2] = pkbf(a0.z, a1.z); p1[3] = pkbf(a0.w, a1.w);
        p2[0] = pkbf(c0.x, c1.x); p2[1] = pkbf(c0.y, c1.y);
        p2[2] = pkbf(c0.z, c1.z); p2[3] = pkbf(c0.w, c1.w);
        #pragma unroll
        for (int i = 0; i < 4; i++) {
            int n_loc = nc * 4 + i;
            int idx = n_loc * 32 + ((chunk ^ (n_loc & 7)) << 2) + within;
            B1p[idx] = p1[i];
            B2p[idx] = p2[i];
        }
        __syncthreads();
        if (k0 + 64 < DMODEL) {
            const float* Bn = B + (size_t)(k0 + 64 + 2 * kp) * 8192 + bx + nc * 4;
            a0 = *(const float4*)(Bn);
            a1 = *(const float4*)(Bn + 8192);
            c0 = *(const float4*)(Bn + 4096);
            c1 = *(const float4*)(Bn + 4096 + 8192);
        }
        #pragma unroll
        for (int ks = 0; ks < 2; ks++) {
            bf16x8 af[4];
            #pragma unroll
            for (int m = 0; m < 4; m++) {
                int row = wid * 64 + m * 16 + (l & 15);
                int sl = (ks * 4 + g) ^ (row & 7);
                af[m] = *(const bf16x8*)&As[row * 64 + sl * 8];
            }
            #pragma unroll
            for (int nf = 0; nf < 2; nf++) {
                int n_loc = nf * 16 + (l & 15);
                int base = n_loc * 32 + (((ks * 4 + g) ^ (n_loc & 7)) << 2);
                bf16x8 b1 = *(const bf16x8*)&B1p[base];
                bf16x8 b2 = *(const bf16x8*)&B2p[base];
                #pragma unroll
                for (int m = 0; m < 4; m++) {
                    acc1[m][nf] = __builtin_amdgcn_mfma_f32_16x16x32_bf16(af[m], b1, acc1[m][nf], 0, 0, 0);
                    acc2[m][nf] = __builtin_amdgcn_mfma_f32_16x16x32_bf16(af[m], b2, acc2[m][nf], 0, 0, 0);
                }
            }
        }
        __syncthreads();
    }
    #pragma unroll
    for (int m = 0; m < 4; m++) {
        int row0 = wid * 64 + m * 16 + g * 4;
        #pragma unroll
        for (int nf = 0; nf < 2; nf++) {
            int col = bx + nf * 16 + (l & 15);
            #pragma unroll
            for (int r = 0; r < 4; r++) {
                float h1 = acc1[m][nf][r], h2 = acc2[m][nf][r];
                float sil = h2 / (1.0f + __expf(-h2));
                C[(size_t)(row0 + r) * DFF + col] = f2bf(h1 * sil);
            }
        }
    }
}

// ---------------- per-expert top-CAP via bitonic sort ----------------
__global__ __launch_bounds__(1024) void expert_select_kernel(const float* __restrict__ wfull,
                                                             float* __restrict__ sw,
                                                             int* __restrict__ sidx,
                                                             int* __restrict__ slot) {
    __shared__ unsigned long long keys[2048];
    int e = blockIdx.x;
    int t = threadIdx.x;
    for (int i = t; i < 2048; i += 1024) {
        float w = wfull[i * 8 + e];
        unsigned int wb = __float_as_uint(w);
        keys[i] = ((unsigned long long)wb << 32) | (unsigned long long)(0xFFFFFFFFu - (unsigned int)i);
    }
    __syncthreads();
    for (int k = 2; k <= 2048; k <<= 1) {
        for (int j = k >> 1; j > 0; j >>= 1) {
            for (int i = t; i < 2048; i += 1024) {
                int ixj = i ^ j;
                if (ixj > i) {
                    bool desc = ((i & k) == 0);
                    unsigned long long a = keys[i], b = keys[ixj];
                    if ((a < b) == desc) { keys[i] = b; keys[ixj] = a; }
                }
            }
            __syncthreads();
        }
    }
    if (t < CAP) {
        unsigned long long kk = keys[t];
        float w = __uint_as_float((unsigned int)(kk >> 32));
        int idx = (int)(0xFFFFFFFFu - (unsigned int)(kk & 0xFFFFFFFFu));
        sw[e * CAP + t] = w;
        sidx[e * CAP + t] = idx;
        if (w > 0.f) slot[idx * 8 + e] = t;
    }
}

// ---------------- gather tokens -> bf16 ----------------
__global__ __launch_bounds__(256) void gather_tok_kernel(const float* __restrict__ hn,
                                                         const int* __restrict__ sidx,
                                                         const float* __restrict__ sw,
                                                         unsigned short* __restrict__ tok) {
    int ec = blockIdx.x;
    int tid = threadIdx.x;
    float w = sw[ec];
    int src = sidx[ec];
    const float* s = hn + (size_t)src * DMODEL;
    unsigned short* d = tok + (size_t)ec * DMODEL;
    for (int i = tid; i < DMODEL; i += 256) d[i] = (w > 0.f) ? f2bf(s[i]) : 0;
}

// ---------------- final combine ----------------
__global__ __launch_bounds__(256) void combine_kernel(const float* __restrict__ h,
                                                      const float* __restrict__ out_e,
                                                      const int* __restrict__ slot,
                                                      const float* __restrict__ wfull,
                                                      const float* __restrict__ gate_sum,
                                                      float* __restrict__ out) {
    int t = blockIdx.x;
    int tid = threadIdx.x;
    for (int d = tid; d < DMODEL; d += 256) {
        float acc = h[(size_t)t * DMODEL + d];
        #pragma unroll
        for (int e = 0; e < 8; e++) {
            int c = slot[t * 8 + e];
            if (c >= 0) acc += wfull[t * 8 + e] * out_e[((size_t)(e * CAP + c)) * DMODEL + d];
        }
        out[(size_t)t * DMODEL + d] = acc;
    }
    if (t == 0 && tid == 0) {
        float a = 0.f;
        #pragma unroll
        for (int e = 0; e < 8; e++) { float m = gate_sum[e] / (float)T_TOK; a += m * m; }
        out[(size_t)T_TOK * DMODEL] = 8.0f * a;
    }
}

extern "C" void kernel_launch(void* const* d_in, const int* in_sizes, int n_in,
                              void* d_out, int out_size, void* d_ws, size_t ws_size,
                              hipStream_t stream) {
    const float* x     = (const float*)d_in[0];
    const int*   gtm   = (const int*)d_in[2];
    const float* Wq    = (const float*)d_in[3];
    const float* Wk    = (const float*)d_in[4];
    const float* Wv    = (const float*)d_in[5];
    const float* Wo    = (const float*)d_in[6];
    const float* g1    = (const float*)d_in[7];
    const float* g2    = (const float*)d_in[8];
    const float* Wgate = (const float*)d_in[9];
    const float* W1    = (const float*)d_in[10];
    const float* W2    = (const float*)d_in[11];
    float* out = (float*)d_out;

    char* ws = (char*)d_ws;
    unsigned short* Qh   = (unsigned short*)(ws + 0);
    unsigned short* Ql   = (unsigned short*)(ws + 4194304);
    unsigned short* Kh   = (unsigned short*)(ws + 8388608);
    unsigned short* Kl   = (unsigned short*)(ws + 12582912);
    unsigned short* Vtb  = (unsigned short*)(ws + 16777216);
    unsigned short* act  = (unsigned short*)(ws + 0);           // MoE phase; Q/K dead
    unsigned short* xn   = (unsigned short*)(ws + 20971520);
    unsigned short* attno= (unsigned short*)(ws + 25165824);
    float* hb    = (float*)(ws + 29360128);
    float* hnb   = (float*)(ws + 37748736);
    float* oute  = (float*)(ws + 46137344);
    unsigned short* tok = (unsigned short*)(ws + 54525952);
    float* ropec = (float*)(ws + 58720256);
    float* ropes = (float*)(ws + 58851328);
    float* wfull = (float*)(ws + 58982400);
    int*   slot  = (int*)(ws + 59047936);
    float* sw    = (float*)(ws + 59113472);
    int*   sidx  = (int*)(ws + 59121664);
    float* gsum  = (float*)(ws + 59129856);
    int*   gidx  = (int*)(ws + 59131904);
    int*   gcnt  = (int*)(ws + 59133952);
    unsigned short* Kgh = (unsigned short*)(ws + 59140096);     // 512 KB
    unsigned short* Kgl = (unsigned short*)(ws + 59664384);     // 512 KB
    unsigned short* Vgt = (unsigned short*)(ws + 60188672);     // 512 KB
    unsigned short* Qgh = (unsigned short*)(ws + 60712960);     // 512 KB
    unsigned short* Qgl = (unsigned short*)(ws + 61237248);     // 512 KB

    rope_table_kernel<<<S_LEN, 32, 0, stream>>>(ropec, ropes, gsum);
    gscan_kernel<<<2, 1024, 0, stream>>>(gtm, gidx, gcnt);
    rmsnorm_kernel<1><<<T_TOK, 256, 0, stream>>>(x, g1, xn);

    gemm_qkv_rope<<<dim3(48, 16, 1), 256, 0, stream>>>(
        xn, Wq, Wk, Wv, ropec, ropes, Qh, Ql, Kh, Kl, Vtb);

    gather_gkv_kernel<<<32, 256, 0, stream>>>(
        Qh, Ql, Kh, Kl, Vtb, gidx, gcnt, Qgh, Qgl, Kgh, Kgl, Vgt);

    attn_mfma_kernel<<<dim3(16, 16, 2), 256, 0, stream>>>(
        Qh, Ql, Kh, Kl, Vtb, Kgh, Kgl, Vgt, gtm, gcnt, attno);

    attn_gq_kernel<<<dim3(2, 16, 2), 256, 0, stream>>>(
        Qgh, Qgl, Kh, Kl, Vtb, gidx, gcnt, attno);

    // h = x + attno @ Wo  (f32 Wo read directly)
    gemm_bf32<1><<<dim3(32, 16, 1), 256, 0, stream>>>(
        attno, Wo, x, hb, 1024, 1024, 0, 0, 0);

    rmsnorm_kernel<0><<<T_TOK, 256, 0, stream>>>(hb, g2, hnb);
    gate_kernel<<<T_TOK / 4, 256, 0, stream>>>(hnb, Wgate, wfull, slot, gsum);
    expert_select_kernel<<<NE, 1024, 0, stream>>>(wfull, sw, sidx, slot);
    gather_tok_kernel<<<NE * CAP, 256, 0, stream>>>(hnb, sidx, sw, tok);

    gemm_w1_fused<<<dim3(128, 8, 1), 256, 0, stream>>>(tok, W1, act);
    gemm_bf32<0><<<dim3(32, 2, 8), 256, 0, stream>>>(
        act, W2, nullptr, oute, 4096, 4096,
        (long long)CAP * DFF, (long long)DFF * 1024, (long long)CAP * 1024);

    combine_kernel<<<T_TOK, 256, 0, stream>>>(hb, oute, slot, wfull, gsum, out);
}

// Round 15
// 352.542 us; speedup vs baseline: 2.0822x; 1.0653x over previous
//
#include <hip/hip_runtime.h>
#include <hip/hip_bf16.h>
#include <math.h>

#define T_TOK 2048
#define DMODEL 1024
#define NH 16
#define HD 64
#define S_LEN 1024
#define NE 8
#define CAP 256
#define DFF 4096

typedef __attribute__((ext_vector_type(8))) short bf16x8;
typedef __attribute__((ext_vector_type(4))) float f32x4;

__device__ inline unsigned short f2bf(float f) {
    union { float f; unsigned int u; } x; x.f = f;
    unsigned int u = x.u;
    unsigned int r = (u + 0x7FFFu + ((u >> 16) & 1u)) >> 16;
    return (unsigned short)r;
}

__device__ inline float bf2f(unsigned short h) {
    union { unsigned int u; float f; } x; x.u = (unsigned int)h << 16; return x.f;
}

// packed f32x2 -> bf16x2 (RTNE); lo in low 16 bits
__device__ inline unsigned int pkbf(float lo, float hi) {
    __hip_bfloat162 h2 = __float22bfloat162_rn(make_float2(lo, hi));
    unsigned int r;
    __builtin_memcpy(&r, &h2, 4);
    return r;
}

__device__ inline void gload16(const void* g, void* l) {
    __builtin_amdgcn_global_load_lds(
        (const __attribute__((address_space(1))) unsigned int*)g,
        (__attribute__((address_space(3))) unsigned int*)l, 16, 0, 0);
}

// ---------------- RMSNorm (OUTBF: 1 -> bf16 out, 0 -> f32 out); optionally zero gsum ----------------
template <int OUTBF>
__global__ __launch_bounds__(256) void rmsnorm_kernel(const float* __restrict__ x,
                                                      const float* __restrict__ g,
                                                      void* __restrict__ yv,
                                                      float* __restrict__ gsum) {
    __shared__ float red[256];
    int t = blockIdx.x;
    int tid = threadIdx.x;
    if (gsum && t == 0 && tid < 8) gsum[tid] = 0.f;
    const float* xr = x + (size_t)t * DMODEL;
    float ss = 0.f;
    for (int d = tid; d < DMODEL; d += 256) { float v = xr[d]; ss += v * v; }
    red[tid] = ss; __syncthreads();
    for (int o = 128; o > 0; o >>= 1) { if (tid < o) red[tid] += red[tid + o]; __syncthreads(); }
    float scale = 1.0f / sqrtf(red[0] / (float)DMODEL + 1e-6f);
    if (OUTBF) {
        unsigned short* yr = (unsigned short*)yv + (size_t)t * DMODEL;
        for (int d = tid; d < DMODEL; d += 256) yr[d] = f2bf(g[d] * xr[d] * scale);
    } else {
        float* yr = (float*)yv + (size_t)t * DMODEL;
        for (int d = tid; d < DMODEL; d += 256) yr[d] = g[d] * xr[d] * scale;
    }
}

// ---------------- gate: one wave per token, register-only; writes wfull + slot=-1 ----------------
__global__ __launch_bounds__(256) void gate_kernel(const float* __restrict__ hn,
                                                   const float* __restrict__ Wgate,
                                                   float* __restrict__ wfull,
                                                   int* __restrict__ slot,
                                                   float* __restrict__ gate_sum) {
    int tid = threadIdx.x;
    int w = tid >> 6, l = tid & 63;
    int t = blockIdx.x * 4 + w;
    int e = l & 7, g = l >> 3;
    const float* xr = hn + (size_t)t * DMODEL;
    const float* wp = Wgate + l;
    float acc = 0.f;
    #pragma unroll 8
    for (int kk = 0; kk < 128; kk++)
        acc += xr[g + 8 * kk] * wp[64 * kk];
    #pragma unroll
    for (int o = 8; o < 64; o <<= 1) acc += __shfl_xor(acc, o, 64);
    float m = acc;
    #pragma unroll
    for (int o = 1; o < 8; o <<= 1) m = fmaxf(m, __shfl_xor(m, o, 64));
    float p = __expf(acc - m);
    float s = p;
    #pragma unroll
    for (int o = 1; o < 8; o <<= 1) s += __shfl_xor(s, o, 64);
    float pr = p / s;
    unsigned long long key = ((unsigned long long)__float_as_uint(pr) << 32) | (unsigned)(7 - e);
    unsigned long long k1 = key;
    #pragma unroll
    for (int o = 1; o < 8; o <<= 1) { unsigned long long t2 = __shfl_xor(k1, o, 64); if (t2 > k1) k1 = t2; }
    int e1 = 7 - (int)(k1 & 7);
    unsigned long long key2 = (e == e1) ? 0ull : key;
    unsigned long long k2 = key2;
    #pragma unroll
    for (int o = 1; o < 8; o <<= 1) { unsigned long long t2 = __shfl_xor(k2, o, 64); if (t2 > k2) k2 = t2; }
    int e2 = 7 - (int)(k2 & 7);
    if (l < 8) {
        wfull[t * 8 + e] = (e == e1 || e == e2) ? pr : 0.f;
        slot[t * 8 + e] = -1;
        atomicAdd(&gate_sum[e], pr);
    }
}

// ---------------- fused QKV GEMM + inline RoPE + hi/lo + V-transpose (B reg-prefetch) ----------------
__global__ __launch_bounds__(256) void gemm_qkv_rope(const unsigned short* __restrict__ xn,
                                                     const float* __restrict__ Wq,
                                                     const float* __restrict__ Wk,
                                                     const float* __restrict__ Wv,
                                                     unsigned short* __restrict__ Qh,
                                                     unsigned short* __restrict__ Ql,
                                                     unsigned short* __restrict__ Kh,
                                                     unsigned short* __restrict__ Kl,
                                                     unsigned short* __restrict__ Vtb) {
    __shared__ unsigned short As[128 * 64];
    __shared__ unsigned int Bp[64 * 32];
    const int mat = blockIdx.x >> 4;
    const int h = blockIdx.x & 15;
    const float* B = ((mat == 0) ? Wq : (mat == 1) ? Wk : Wv) + h * 64;
    const int by = blockIdx.y * 128;
    const int tid = threadIdx.x, l = tid & 63, wid = tid >> 6;
    const int g = l >> 4;
    const int kp = tid >> 3;
    const int nc = tid & 7;
    const int chunk = kp >> 2, within = kp & 3;

    f32x4 acc[2][4] = {};

    const float* Brow = B + (size_t)(2 * kp) * 1024 + nc * 8;
    float4 a0 = *(const float4*)(Brow);
    float4 a1 = *(const float4*)(Brow + 4);
    float4 b0 = *(const float4*)(Brow + 1024);
    float4 b1 = *(const float4*)(Brow + 1028);

    for (int k0 = 0; k0 < 1024; k0 += 64) {
        #pragma unroll
        for (int i = 0; i < 4; i++) {
            int c = i * 256 + tid;
            int row = c >> 3, sl = c & 7, gs = sl ^ (row & 7);
            gload16(xn + (size_t)(by + row) * 1024 + k0 + gs * 8, &As[c * 8]);
        }
        unsigned int p[8];
        p[0] = pkbf(a0.x, b0.x); p[1] = pkbf(a0.y, b0.y);
        p[2] = pkbf(a0.z, b0.z); p[3] = pkbf(a0.w, b0.w);
        p[4] = pkbf(a1.x, b1.x); p[5] = pkbf(a1.y, b1.y);
        p[6] = pkbf(a1.z, b1.z); p[7] = pkbf(a1.w, b1.w);
        #pragma unroll
        for (int i = 0; i < 8; i++) {
            int n_loc = nc * 8 + i;
            int idx = n_loc * 32 + ((chunk ^ (n_loc & 7)) << 2) + within;
            Bp[idx] = p[i];
        }
        __syncthreads();
        if (k0 + 64 < 1024) {
            const float* Bn = B + (size_t)(k0 + 64 + 2 * kp) * 1024 + nc * 8;
            a0 = *(const float4*)(Bn);
            a1 = *(const float4*)(Bn + 4);
            b0 = *(const float4*)(Bn + 1024);
            b1 = *(const float4*)(Bn + 1028);
        }
        #pragma unroll
        for (int ks = 0; ks < 2; ks++) {
            bf16x8 af[2];
            #pragma unroll
            for (int m = 0; m < 2; m++) {
                int row = wid * 32 + m * 16 + (l & 15);
                int sl = (ks * 4 + g) ^ (row & 7);
                af[m] = *(const bf16x8*)&As[row * 64 + sl * 8];
            }
            #pragma unroll
            for (int nf = 0; nf < 4; nf++) {
                int n_loc = nf * 16 + (l & 15);
                int base = n_loc * 32 + (((ks * 4 + g) ^ (n_loc & 7)) << 2);
                bf16x8 bfr = *(const bf16x8*)&Bp[base];
                #pragma unroll
                for (int m = 0; m < 2; m++)
                    acc[m][nf] = __builtin_amdgcn_mfma_f32_16x16x32_bf16(af[m], bfr, acc[m][nf], 0, 0, 0);
            }
        }
        __syncthreads();
    }

    if (mat < 2) {
        unsigned short* Dh = (mat == 0) ? Qh : Kh;
        unsigned short* Dl = (mat == 0) ? Ql : Kl;
        float scale = (mat == 0) ? 0.125f : 1.0f;
        #pragma unroll
        for (int m = 0; m < 2; m++)
            #pragma unroll
            for (int r = 0; r < 4; r++) {
                int t = by + wid * 32 + m * 16 + g * 4 + r;
                int b = t >> 10, s = t & 1023;
                size_t ob = ((size_t)(b * 16 + h) * 1024 + s) * 64;
                #pragma unroll
                for (int pr = 0; pr < 2; pr++) {
                    int i = pr * 16 + (l & 15);
                    // inline RoPE table math (identical formula to the old table kernel)
                    float invf = powf(10000.0f, -(float)(2 * i) / 64.0f);
                    float ang = (float)s * invf;
                    float c = cosf(ang), sn = sinf(ang);
                    float a = acc[m][pr][r], bb = acc[m][pr + 2][r];
                    float v0 = (a * c - bb * sn) * scale;
                    float v1 = (bb * c + a * sn) * scale;
                    unsigned short h0 = f2bf(v0), h1 = f2bf(v1);
                    Dh[ob + i] = h0;      Dl[ob + i] = f2bf(v0 - bf2f(h0));
                    Dh[ob + i + 32] = h1; Dl[ob + i + 32] = f2bf(v1 - bf2f(h1));
                }
            }
    } else {
        #pragma unroll
        for (int m = 0; m < 2; m++) {
            int t0 = by + wid * 32 + m * 16 + g * 4;
            int b = t0 >> 10, s0 = t0 & 1023;
            #pragma unroll
            for (int nf = 0; nf < 4; nf++) {
                int d = nf * 16 + (l & 15);
                unsigned short tmp[4];
                #pragma unroll
                for (int r = 0; r < 4; r++) tmp[r] = f2bf(acc[m][nf][r]);
                *(uint2*)&Vtb[((size_t)(b * 16 + h) * 64 + d) * 1024 + s0] = *(uint2*)tmp;
            }
        }
    }
}

// ---------------- dense flash attention, double-buffered K/V + setprio ----------------
__global__ __launch_bounds__(256) void attn_mfma_kernel(const unsigned short* __restrict__ Qh,
                                                        const unsigned short* __restrict__ Ql,
                                                        const unsigned short* __restrict__ Kh,
                                                        const unsigned short* __restrict__ Kl,
                                                        const unsigned short* __restrict__ Vtb,
                                                        const int* __restrict__ gtm,
                                                        unsigned short* __restrict__ o) {
    __shared__ unsigned short Ksh[2][64 * 64];
    __shared__ unsigned short Ksl[2][64 * 64];
    __shared__ unsigned short Vs[2][64 * 64];
    __shared__ unsigned short Pl[4][16 * 64];
    const int qt = blockIdx.x, h = blockIdx.y, b = blockIdx.z;
    const int bh = b * 16 + h;
    const int tid = threadIdx.x, l = tid & 63, w = tid >> 6;
    const int q0 = qt * 64 + w * 16;
    const unsigned short* Qhb = Qh + (size_t)bh * 1024 * 64;
    const unsigned short* Qlb = Ql + (size_t)bh * 1024 * 64;
    const unsigned short* Khb = Kh + (size_t)bh * 1024 * 64;
    const unsigned short* Klb = Kl + (size_t)bh * 1024 * 64;
    const unsigned short* Vbh = Vtb + (size_t)bh * 64 * 1024;
    const int* gb = gtm + b * 1024;

    bf16x8 afh[2], afl[2];
    #pragma unroll
    for (int ks = 0; ks < 2; ks++) {
        size_t off = (size_t)(q0 + (l & 15)) * 64 + ks * 32 + (l >> 4) * 8;
        afh[ks] = *(const bf16x8*)(Qhb + off);
        afl[ks] = *(const bf16x8*)(Qlb + off);
    }

    int gqm = 0;
    #pragma unroll
    for (int r = 0; r < 4; r++)
        gqm |= (gb[q0 + (l >> 4) * 4 + r] ? 1 : 0) << r;

    f32x4 acc_o[4] = {};
    float m_run[4], l_run[4];
    #pragma unroll
    for (int r = 0; r < 4; r++) { m_run[r] = -1e30f; l_run[r] = 0.f; }

    // prologue: issue tile 0 into buffer 0
    {
        #pragma unroll
        for (int i = 0; i < 2; i++) {
            int c = i * 256 + tid, row = c >> 3, sl = c & 7, gs = sl ^ (row & 7);
            gload16(Khb + (size_t)row * 64 + gs * 8, &Ksh[0][c * 8]);
            gload16(Klb + (size_t)row * 64 + gs * 8, &Ksl[0][c * 8]);
            gload16(Vbh + (size_t)row * 1024 + gs * 8, &Vs[0][c * 8]);
        }
    }
    int cur = 0;

    for (int jt = 0; jt < 16; jt++) {
        const int j0 = jt * 64;
        __syncthreads();

        if (jt < 15) {
            const int jn = j0 + 64;
            int nb = cur ^ 1;
            #pragma unroll
            for (int i = 0; i < 2; i++) {
                int c = i * 256 + tid, row = c >> 3, sl = c & 7, gs = sl ^ (row & 7);
                gload16(Khb + (size_t)(jn + row) * 64 + gs * 8, &Ksh[nb][c * 8]);
                gload16(Klb + (size_t)(jn + row) * 64 + gs * 8, &Ksl[nb][c * 8]);
                gload16(Vbh + (size_t)row * 1024 + jn + gs * 8, &Vs[nb][c * 8]);
            }
        }

        f32x4 sv[4] = {};
        __builtin_amdgcn_s_setprio(1);
        #pragma unroll
        for (int n = 0; n < 4; n++) {
            #pragma unroll
            for (int ks = 0; ks < 2; ks++) {
                int row = n * 16 + (l & 15);
                int sl = (ks * 4 + (l >> 4)) ^ (row & 7);
                bf16x8 khf = *(const bf16x8*)&Ksh[cur][row * 64 + sl * 8];
                bf16x8 klf = *(const bf16x8*)&Ksl[cur][row * 64 + sl * 8];
                sv[n] = __builtin_amdgcn_mfma_f32_16x16x32_bf16(afl[ks], khf, sv[n], 0, 0, 0);
                sv[n] = __builtin_amdgcn_mfma_f32_16x16x32_bf16(afh[ks], klf, sv[n], 0, 0, 0);
                sv[n] = __builtin_amdgcn_mfma_f32_16x16x32_bf16(afh[ks], khf, sv[n], 0, 0, 0);
            }
        }
        __builtin_amdgcn_s_setprio(0);

        int gk[4];
        #pragma unroll
        for (int n = 0; n < 4; n++) gk[n] = gb[j0 + n * 16 + (l & 15)];

        #pragma unroll
        for (int n = 0; n < 4; n++)
            #pragma unroll
            for (int r = 0; r < 4; r++) {
                int q = q0 + (l >> 4) * 4 + r;
                int k = j0 + n * 16 + (l & 15);
                bool allowed = ((gqm >> r) & 1) || gk[n] || ((k <= q) && (q - k < 256));
                if (!allowed) sv[n][r] = -1e30f;
            }

        {
            float tm[4], corr[4], rsum[4];
            #pragma unroll
            for (int r = 0; r < 4; r++)
                tm[r] = fmaxf(fmaxf(sv[0][r], sv[1][r]), fmaxf(sv[2][r], sv[3][r]));
            #pragma unroll
            for (int wd = 1; wd <= 8; wd <<= 1)
                #pragma unroll
                for (int r = 0; r < 4; r++) tm[r] = fmaxf(tm[r], __shfl_xor(tm[r], wd, 64));
            #pragma unroll
            for (int r = 0; r < 4; r++) {
                float mn = fmaxf(m_run[r], tm[r]);
                corr[r] = __expf(m_run[r] - mn);
                m_run[r] = mn;
                rsum[r] = 0.f;
            }
            #pragma unroll
            for (int n = 0; n < 4; n++)
                #pragma unroll
                for (int r = 0; r < 4; r++) {
                    float p = __expf(sv[n][r] - m_run[r]);
                    sv[n][r] = p;
                    rsum[r] += p;
                }
            #pragma unroll
            for (int wd = 1; wd <= 8; wd <<= 1)
                #pragma unroll
                for (int r = 0; r < 4; r++) rsum[r] += __shfl_xor(rsum[r], wd, 64);
            #pragma unroll
            for (int r = 0; r < 4; r++) l_run[r] = l_run[r] * corr[r] + rsum[r];
            #pragma unroll
            for (int nd = 0; nd < 4; nd++)
                #pragma unroll
                for (int r = 0; r < 4; r++) acc_o[nd][r] *= corr[r];
            #pragma unroll
            for (int n = 0; n < 4; n++)
                #pragma unroll
                for (int r = 0; r < 4; r++) {
                    int qr = (l >> 4) * 4 + r;
                    int kc = n * 16 + (l & 15);
                    int byte = (qr * 128 + kc * 2) ^ ((qr & 7) << 4);
                    Pl[w][byte >> 1] = f2bf(sv[n][r]);
                }
        }

        asm volatile("s_waitcnt lgkmcnt(0)" ::: "memory");
        __builtin_amdgcn_sched_barrier(0);

        __builtin_amdgcn_s_setprio(1);
        #pragma unroll
        for (int ks = 0; ks < 2; ks++) {
            int prow = l & 15;
            int psl = (ks * 4 + (l >> 4)) ^ (prow & 7);
            bf16x8 pa = *(const bf16x8*)&Pl[w][prow * 64 + psl * 8];
            #pragma unroll
            for (int nd = 0; nd < 4; nd++) {
                int row = nd * 16 + (l & 15);
                int sl = (ks * 4 + (l >> 4)) ^ (row & 7);
                bf16x8 vf = *(const bf16x8*)&Vs[cur][row * 64 + sl * 8];
                acc_o[nd] = __builtin_amdgcn_mfma_f32_16x16x32_bf16(pa, vf, acc_o[nd], 0, 0, 0);
            }
        }
        __builtin_amdgcn_s_setprio(0);
        cur ^= 1;
    }

    #pragma unroll
    for (int r = 0; r < 4; r++) {
        float inv = 1.0f / l_run[r];
        int t_ = b * 1024 + q0 + (l >> 4) * 4 + r;
        #pragma unroll
        for (int nd = 0; nd < 4; nd++) {
            int col = h * 64 + nd * 16 + (l & 15);
            o[(size_t)t_ * 1024 + col] = f2bf(acc_o[nd][r] * inv);
        }
    }
}

// ---------------- generic fused GEMM: C(f32) = A(bf16) @ B(f32), B reg-prefetch ----------------
template <int RES>
__global__ __launch_bounds__(256) void gemm_bf32(const unsigned short* __restrict__ A,
                                                 const float* __restrict__ B,
                                                 const float* __restrict__ Rr,
                                                 float* __restrict__ C,
                                                 int K, int lda,
                                                 long long sA, long long sB, long long sC) {
    __shared__ unsigned short As[128 * 64];
    __shared__ unsigned int Bp[32 * 32];
    A += (long long)blockIdx.z * sA + (long long)blockIdx.y * 128 * lda;
    B += (long long)blockIdx.z * sB;
    C += (long long)blockIdx.z * sC + (long long)blockIdx.y * 128 * 1024;
    const float* Rp = RES ? (Rr + (long long)blockIdx.y * 128 * 1024) : nullptr;
    const int bx = blockIdx.x * 32;
    const int tid = threadIdx.x, l = tid & 63, wid = tid >> 6;
    const int g = l >> 4;
    const int kp = tid >> 3;
    const int nc = tid & 7;
    const int chunk = kp >> 2, within = kp & 3;

    f32x4 acc[2][2] = {};

    const float* Brow = B + (size_t)(2 * kp) * 1024 + bx + nc * 4;
    float4 a0 = *(const float4*)(Brow);
    float4 a1 = *(const float4*)(Brow + 1024);

    for (int k0 = 0; k0 < K; k0 += 64) {
        #pragma unroll
        for (int i = 0; i < 4; i++) {
            int c = i * 256 + tid;
            int row = c >> 3, sl = c & 7, gs = sl ^ (row & 7);
            gload16(A + (size_t)row * lda + k0 + gs * 8, &As[c * 8]);
        }
        unsigned int p1[4];
        p1[0] = pkbf(a0.x, a1.x); p1[1] = pkbf(a0.y, a1.y);
        p1[2] = pkbf(a0.z, a1.z); p1[3] = pkbf(a0.w, a1.w);
        #pragma unroll
        for (int i = 0; i < 4; i++) {
            int n_loc = nc * 4 + i;
            int idx = n_loc * 32 + ((chunk ^ (n_loc & 7)) << 2) + within;
            Bp[idx] = p1[i];
        }
        __syncthreads();
        if (k0 + 64 < K) {
            const float* Bn = B + (size_t)(k0 + 64 + 2 * kp) * 1024 + bx + nc * 4;
            a0 = *(const float4*)(Bn);
            a1 = *(const float4*)(Bn + 1024);
        }
        #pragma unroll
        for (int ks = 0; ks < 2; ks++) {
            bf16x8 af[2];
            #pragma unroll
            for (int m = 0; m < 2; m++) {
                int row = wid * 32 + m * 16 + (l & 15);
                int sl = (ks * 4 + g) ^ (row & 7);
                af[m] = *(const bf16x8*)&As[row * 64 + sl * 8];
            }
            #pragma unroll
            for (int nf = 0; nf < 2; nf++) {
                int n_loc = nf * 16 + (l & 15);
                int base = n_loc * 32 + (((ks * 4 + g) ^ (n_loc & 7)) << 2);
                bf16x8 bfr = *(const bf16x8*)&Bp[base];
                #pragma unroll
                for (int m = 0; m < 2; m++)
                    acc[m][nf] = __builtin_amdgcn_mfma_f32_16x16x32_bf16(af[m], bfr, acc[m][nf], 0, 0, 0);
            }
        }
        __syncthreads();
    }
    #pragma unroll
    for (int m = 0; m < 2; m++) {
        int row0 = wid * 32 + m * 16 + g * 4;
        #pragma unroll
        for (int nf = 0; nf < 2; nf++) {
            int col = bx + nf * 16 + (l & 15);
            #pragma unroll
            for (int r = 0; r < 4; r++) {
                size_t idx = (size_t)(row0 + r) * 1024 + col;
                float v = acc[m][nf][r];
                if (RES) v += Rp[idx];
                C[idx] = v;
            }
        }
    }
}

// ---------------- fused MoE W1 GEMM + SwiGLU (B reg-prefetch) ----------------
__global__ __launch_bounds__(256) void gemm_w1_fused(const unsigned short* __restrict__ tok,
                                                     const float* __restrict__ W1,
                                                     unsigned short* __restrict__ act) {
    __shared__ unsigned short As[256 * 64];
    __shared__ unsigned int B1p[32 * 32];
    __shared__ unsigned int B2p[32 * 32];
    const int e = blockIdx.y;
    const int bx = blockIdx.x * 32;
    const unsigned short* A = tok + (size_t)e * CAP * DMODEL;
    const float* B = W1 + (size_t)e * DMODEL * (2 * DFF);
    unsigned short* C = act + (size_t)e * CAP * DFF;
    const int tid = threadIdx.x, l = tid & 63, wid = tid >> 6;
    const int g = l >> 4;
    const int kp = tid >> 3;
    const int nc = tid & 7;
    const int chunk = kp >> 2, within = kp & 3;

    f32x4 acc1[4][2] = {};
    f32x4 acc2[4][2] = {};

    const float* Brow = B + (size_t)(2 * kp) * 8192 + bx + nc * 4;
    float4 a0 = *(const float4*)(Brow);
    float4 a1 = *(const float4*)(Brow + 8192);
    float4 c0 = *(const float4*)(Brow + 4096);
    float4 c1 = *(const float4*)(Brow + 4096 + 8192);

    for (int k0 = 0; k0 < DMODEL; k0 += 64) {
        #pragma unroll
        for (int i = 0; i < 8; i++) {
            int c = i * 256 + tid;
            int row = c >> 3, sl = c & 7, gs = sl ^ (row & 7);
            gload16(A + (size_t)row * DMODEL + k0 + gs * 8, &As[c * 8]);
        }
        unsigned int p1[4], p2[4];
        p1[0] = pkbf(a0.x, a1.x); p1[1] = pkbf(a0.y, a1.y);
        p1[2] = pkbf(a0.z, a1.z); p1[3] = pkbf(a0.w, a1.w);
        p2[0] = pkbf(c0.x, c1.x); p2[1] = pkbf(c0.y, c1.y);
        p2[2] = pkbf(c0.z, c1.z); p2[3] = pkbf(c0.w, c1.w);
        #pragma unroll
        for (int i = 0; i < 4; i++) {
            int n_loc = nc * 4 + i;
            int idx = n_loc * 32 + ((chunk ^ (n_loc & 7)) << 2) + within;
            B1p[idx] = p1[i];
            B2p[idx] = p2[i];
        }
        __syncthreads();
        if (k0 + 64 < DMODEL) {
            const float* Bn = B + (size_t)(k0 + 64 + 2 * kp) * 8192 + bx + nc * 4;
            a0 = *(const float4*)(Bn);
            a1 = *(const float4*)(Bn + 8192);
            c0 = *(const float4*)(Bn + 4096);
            c1 = *(const float4*)(Bn + 4096 + 8192);
        }
        #pragma unroll
        for (int ks = 0; ks < 2; ks++) {
            bf16x8 af[4];
            #pragma unroll
            for (int m = 0; m < 4; m++) {
                int row = wid * 64 + m * 16 + (l & 15);
                int sl = (ks * 4 + g) ^ (row & 7);
                af[m] = *(const bf16x8*)&As[row * 64 + sl * 8];
            }
            #pragma unroll
            for (int nf = 0; nf < 2; nf++) {
                int n_loc = nf * 16 + (l & 15);
                int base = n_loc * 32 + (((ks * 4 + g) ^ (n_loc & 7)) << 2);
                bf16x8 b1 = *(const bf16x8*)&B1p[base];
                bf16x8 b2 = *(const bf16x8*)&B2p[base];
                #pragma unroll
                for (int m = 0; m < 4; m++) {
                    acc1[m][nf] = __builtin_amdgcn_mfma_f32_16x16x32_bf16(af[m], b1, acc1[m][nf], 0, 0, 0);
                    acc2[m][nf] = __builtin_amdgcn_mfma_f32_16x16x32_bf16(af[m], b2, acc2[m][nf], 0, 0, 0);
                }
            }
        }
        __syncthreads();
    }
    #pragma unroll
    for (int m = 0; m < 4; m++) {
        int row0 = wid * 64 + m * 16 + g * 4;
        #pragma unroll
        for (int nf = 0; nf < 2; nf++) {
            int col = bx + nf * 16 + (l & 15);
            #pragma unroll
            for (int r = 0; r < 4; r++) {
                float h1 = acc1[m][nf][r], h2 = acc2[m][nf][r];
                float sil = h2 / (1.0f + __expf(-h2));
                C[(size_t)(row0 + r) * DFF + col] = f2bf(h1 * sil);
            }
        }
    }
}

// ---------------- per-expert top-CAP via bitonic sort ----------------
__global__ __launch_bounds__(1024) void expert_select_kernel(const float* __restrict__ wfull,
                                                             float* __restrict__ sw,
                                                             int* __restrict__ sidx,
                                                             int* __restrict__ slot) {
    __shared__ unsigned long long keys[2048];
    int e = blockIdx.x;
    int t = threadIdx.x;
    for (int i = t; i < 2048; i += 1024) {
        float w = wfull[i * 8 + e];
        unsigned int wb = __float_as_uint(w);
        keys[i] = ((unsigned long long)wb << 32) | (unsigned long long)(0xFFFFFFFFu - (unsigned int)i);
    }
    __syncthreads();
    for (int k = 2; k <= 2048; k <<= 1) {
        for (int j = k >> 1; j > 0; j >>= 1) {
            for (int i = t; i < 2048; i += 1024) {
                int ixj = i ^ j;
                if (ixj > i) {
                    bool desc = ((i & k) == 0);
                    unsigned long long a = keys[i], b = keys[ixj];
                    if ((a < b) == desc) { keys[i] = b; keys[ixj] = a; }
                }
            }
            __syncthreads();
        }
    }
    if (t < CAP) {
        unsigned long long kk = keys[t];
        float w = __uint_as_float((unsigned int)(kk >> 32));
        int idx = (int)(0xFFFFFFFFu - (unsigned int)(kk & 0xFFFFFFFFu));
        sw[e * CAP + t] = w;
        sidx[e * CAP + t] = idx;
        if (w > 0.f) slot[idx * 8 + e] = t;
    }
}

// ---------------- gather tokens -> bf16 ----------------
__global__ __launch_bounds__(256) void gather_tok_kernel(const float* __restrict__ hn,
                                                         const int* __restrict__ sidx,
                                                         const float* __restrict__ sw,
                                                         unsigned short* __restrict__ tok) {
    int ec = blockIdx.x;
    int tid = threadIdx.x;
    float w = sw[ec];
    int src = sidx[ec];
    const float* s = hn + (size_t)src * DMODEL;
    unsigned short* d = tok + (size_t)ec * DMODEL;
    for (int i = tid; i < DMODEL; i += 256) d[i] = (w > 0.f) ? f2bf(s[i]) : 0;
}

// ---------------- final combine ----------------
__global__ __launch_bounds__(256) void combine_kernel(const float* __restrict__ h,
                                                      const float* __restrict__ out_e,
                                                      const int* __restrict__ slot,
                                                      const float* __restrict__ wfull,
                                                      const float* __restrict__ gate_sum,
                                                      float* __restrict__ out) {
    int t = blockIdx.x;
    int tid = threadIdx.x;
    for (int d = tid; d < DMODEL; d += 256) {
        float acc = h[(size_t)t * DMODEL + d];
        #pragma unroll
        for (int e = 0; e < 8; e++) {
            int c = slot[t * 8 + e];
            if (c >= 0) acc += wfull[t * 8 + e] * out_e[((size_t)(e * CAP + c)) * DMODEL + d];
        }
        out[(size_t)t * DMODEL + d] = acc;
    }
    if (t == 0 && tid == 0) {
        float a = 0.f;
        #pragma unroll
        for (int e = 0; e < 8; e++) { float m = gate_sum[e] / (float)T_TOK; a += m * m; }
        out[(size_t)T_TOK * DMODEL] = 8.0f * a;
    }
}

extern "C" void kernel_launch(void* const* d_in, const int* in_sizes, int n_in,
                              void* d_out, int out_size, void* d_ws, size_t ws_size,
                              hipStream_t stream) {
    const float* x     = (const float*)d_in[0];
    const int*   gtm   = (const int*)d_in[2];
    const float* Wq    = (const float*)d_in[3];
    const float* Wk    = (const float*)d_in[4];
    const float* Wv    = (const float*)d_in[5];
    const float* Wo    = (const float*)d_in[6];
    const float* g1    = (const float*)d_in[7];
    const float* g2    = (const float*)d_in[8];
    const float* Wgate = (const float*)d_in[9];
    const float* W1    = (const float*)d_in[10];
    const float* W2    = (const float*)d_in[11];
    float* out = (float*)d_out;

    char* ws = (char*)d_ws;
    unsigned short* Qh   = (unsigned short*)(ws + 0);
    unsigned short* Ql   = (unsigned short*)(ws + 4194304);
    unsigned short* Kh   = (unsigned short*)(ws + 8388608);
    unsigned short* Kl   = (unsigned short*)(ws + 12582912);
    unsigned short* Vtb  = (unsigned short*)(ws + 16777216);
    unsigned short* act  = (unsigned short*)(ws + 0);           // MoE phase; Q/K dead
    unsigned short* xn   = (unsigned short*)(ws + 20971520);
    unsigned short* attno= (unsigned short*)(ws + 25165824);
    float* hb    = (float*)(ws + 29360128);
    float* hnb   = (float*)(ws + 37748736);
    float* oute  = (float*)(ws + 46137344);
    unsigned short* tok = (unsigned short*)(ws + 54525952);
    float* wfull = (float*)(ws + 58982400);
    int*   slot  = (int*)(ws + 59047936);
    float* sw    = (float*)(ws + 59113472);
    int*   sidx  = (int*)(ws + 59121664);
    float* gsum  = (float*)(ws + 59129856);

    rmsnorm_kernel<1><<<T_TOK, 256, 0, stream>>>(x, g1, xn, nullptr);

    gemm_qkv_rope<<<dim3(48, 16, 1), 256, 0, stream>>>(
        xn, Wq, Wk, Wv, Qh, Ql, Kh, Kl, Vtb);

    attn_mfma_kernel<<<dim3(16, 16, 2), 256, 0, stream>>>(Qh, Ql, Kh, Kl, Vtb, gtm, attno);

    // h = x + attno @ Wo  (f32 Wo read directly)
    gemm_bf32<1><<<dim3(32, 16, 1), 256, 0, stream>>>(
        attno, Wo, x, hb, 1024, 1024, 0, 0, 0);

    rmsnorm_kernel<0><<<T_TOK, 256, 0, stream>>>(hb, g2, hnb, gsum);
    gate_kernel<<<T_TOK / 4, 256, 0, stream>>>(hnb, Wgate, wfull, slot, gsum);
    expert_select_kernel<<<NE, 1024, 0, stream>>>(wfull, sw, sidx, slot);
    gather_tok_kernel<<<NE * CAP, 256, 0, stream>>>(hnb, sidx, sw, tok);

    gemm_w1_fused<<<dim3(128, 8, 1), 256, 0, stream>>>(tok, W1, act);
    gemm_bf32<0><<<dim3(32, 2, 8), 256, 0, stream>>>(
        act, W2, nullptr, oute, 4096, 4096,
        (long long)CAP * DFF, (long long)DFF * 1024, (long long)CAP * 1024);

    combine_kernel<<<T_TOK, 256, 0, stream>>>(hb, oute, slot, wfull, gsum, out);
}